// Round 3
// baseline (3179.074 us; speedup 1.0000x reference)
//
#include <hip/hip_runtime.h>
#include <hip/hip_bf16.h>
#include <math.h>

// Problem constants
#define MTOK   8192   // B*L
#define LSEQ   2048
#define NBATCH 4
#define DMODEL 1024
#define DINNER 2048
#define DSTATE 16
#define DTRANK 64
#define NXZ    4096   // 2*DINNER

__device__ __forceinline__ float silu_f(float x) { return x / (1.f + __expf(-x)); }

// ---------------------------------------------------------------------------
// Generic f32 SGEMM: C[M,N] = A[M,K] @ B[K,N], row-major, strides lda/ldb/ldc.
// BM=BN=128, BK=8, 256 threads, each thread computes 2x2 blocks of 4x4.
// EPI: 0 = none, 1 = softplus(acc + bias[col])  (for delta)
// BN_GUARD: guard B loads / C stores against col >= N (N % 4 == 0 assumed).
// ---------------------------------------------------------------------------
template<int EPI, bool BN_GUARD>
__global__ __launch_bounds__(256)
void sgemm128(const float* __restrict__ A, int lda,
              const float* __restrict__ B, int ldb,
              float* __restrict__ C, int ldc,
              int N, int K, const float* __restrict__ bias)
{
    __shared__ float As[8][132];   // A tile, transposed: As[k][row]
    __shared__ float Bs[8][132];   // B tile: Bs[k][col]

    const int tid  = threadIdx.x;
    const int row0 = blockIdx.x * 128;
    const int col0 = blockIdx.y * 128;

    // staging indices
    const int arow = tid >> 1;            // 0..127
    const int acol = (tid & 1) << 2;      // 0 or 4
    const int brow = tid >> 5;            // 0..7
    const int bcol = (tid & 31) << 2;     // 0..124

    // compute indices
    const int tx = tid & 15;              // col group
    const int ty = tid >> 4;              // row group

    const float* Ag = A + (size_t)(row0 + arow) * lda + acol;
    const float* Bg = B + (size_t)brow * ldb + col0 + bcol;
    const bool bload_ok = !BN_GUARD || (col0 + bcol) < N;

    float acc[2][2][4][4] = {};

    for (int k0 = 0; k0 < K; k0 += 8) {
        float4 av = *(const float4*)(Ag + k0);
        float4 bv = make_float4(0.f, 0.f, 0.f, 0.f);
        if (bload_ok) bv = *(const float4*)(Bg + (size_t)k0 * ldb);

        As[acol + 0][arow] = av.x;
        As[acol + 1][arow] = av.y;
        As[acol + 2][arow] = av.z;
        As[acol + 3][arow] = av.w;
        *(float4*)&Bs[brow][bcol] = bv;
        __syncthreads();

        #pragma unroll
        for (int k = 0; k < 8; ++k) {
            const float4 a0 = *(const float4*)&As[k][ty * 4];
            const float4 a1 = *(const float4*)&As[k][64 + ty * 4];
            const float4 b0 = *(const float4*)&Bs[k][tx * 4];
            const float4 b1 = *(const float4*)&Bs[k][64 + tx * 4];
            const float ar[2][4] = {{a0.x, a0.y, a0.z, a0.w}, {a1.x, a1.y, a1.z, a1.w}};
            const float bc[2][4] = {{b0.x, b0.y, b0.z, b0.w}, {b1.x, b1.y, b1.z, b1.w}};
            #pragma unroll
            for (int i = 0; i < 2; ++i)
                #pragma unroll
                for (int j = 0; j < 2; ++j)
                    #pragma unroll
                    for (int r = 0; r < 4; ++r)
                        #pragma unroll
                        for (int c = 0; c < 4; ++c)
                            acc[i][j][r][c] = fmaf(ar[i][r], bc[j][c], acc[i][j][r][c]);
        }
        __syncthreads();
    }

    #pragma unroll
    for (int i = 0; i < 2; ++i) {
        #pragma unroll
        for (int j = 0; j < 2; ++j) {
            const int col = col0 + j * 64 + tx * 4;
            if (BN_GUARD && col >= N) continue;
            #pragma unroll
            for (int r = 0; r < 4; ++r) {
                const int row = row0 + i * 64 + ty * 4 + r;
                float4 v;
                float* vp = &v.x;
                #pragma unroll
                for (int c = 0; c < 4; ++c) {
                    float t = acc[i][j][r][c];
                    if (EPI == 1) {
                        t += bias[col + c];
                        t = (t > 20.f) ? t : log1pf(expf(t));  // softplus
                    }
                    vp[c] = t;
                }
                *(float4*)(C + (size_t)row * ldc + col) = v;
            }
        }
    }
}

// ---------------------------------------------------------------------------
// Causal depthwise conv (D_CONV=4) + bias + SiLU.
// Reads u_pre = xz[:, 0:2048] (row stride 4096), writes u [MTOK, 2048].
// One thread handles 4 consecutive channels at one (b,l).
// ---------------------------------------------------------------------------
__global__ __launch_bounds__(256)
void conv_silu_kernel(const float* __restrict__ xz,
                      const float* __restrict__ cw,   // [DINNER][4]
                      const float* __restrict__ cb,   // [DINNER]
                      float* __restrict__ u)
{
    const int idx = blockIdx.x * 256 + threadIdx.x;   // [0, MTOK*512)
    const int d4  = idx & 511;
    const int ml  = idx >> 9;                         // b*LSEQ + l
    const int l   = ml & (LSEQ - 1);
    const int d   = d4 << 2;

    float wv[4][4];
    #pragma unroll
    for (int i = 0; i < 4; ++i) {
        const float4 w = *(const float4*)(cw + (size_t)(d + i) * 4);
        wv[i][0] = w.x; wv[i][1] = w.y; wv[i][2] = w.z; wv[i][3] = w.w;
    }

    float4 acc = *(const float4*)(cb + d);
    #pragma unroll
    for (int j = 0; j < 4; ++j) {
        const int ls = l - 3 + j;
        if (ls < 0) continue;
        const float4 xv = *(const float4*)(xz + (size_t)(ml - 3 + j) * NXZ + d);
        acc.x = fmaf(xv.x, wv[0][j], acc.x);
        acc.y = fmaf(xv.y, wv[1][j], acc.y);
        acc.z = fmaf(xv.z, wv[2][j], acc.z);
        acc.w = fmaf(xv.w, wv[3][j], acc.w);
    }
    acc.x = silu_f(acc.x);
    acc.y = silu_f(acc.y);
    acc.z = silu_f(acc.z);
    acc.w = silu_f(acc.w);
    *(float4*)(u + (size_t)ml * DINNER + d) = acc;
}

// ---------------------------------------------------------------------------
// Selective scan + skip (u*Dp) + gate (silu(z)).
// One thread per (b, d); h[16] in registers; B/C tiles staged in LDS.
// delta lives in xz[:, 0:2048] (stride NXZ); z in xz[:, 2048:4096].
// Output yg overwrites delta in-place (same-element RAW within a step).
// ---------------------------------------------------------------------------
__global__ __launch_bounds__(256)
void scan_kernel(const float* __restrict__ u,
                 float* __restrict__ xz,           // delta | z, stride NXZ; yg out
                 const float* __restrict__ proj,   // [MTOK][96], cols 64..95 = B,C
                 const float* __restrict__ A_log,  // [DINNER][16]
                 const float* __restrict__ Dp,     // [DINNER]
                 int dummy)
{
    const int b = blockIdx.y;                       // 0..3
    const int d = blockIdx.x * 256 + threadIdx.x;   // 0..2047

    float Av[DSTATE];
    #pragma unroll
    for (int n = 0; n < DSTATE; ++n)
        Av[n] = -__expf(A_log[(size_t)d * DSTATE + n]);

    float h[DSTATE];
    #pragma unroll
    for (int n = 0; n < DSTATE; ++n) h[n] = 0.f;

    const float Dval = Dp[d];

    __shared__ float Bsh[64][DSTATE];
    __shared__ float Csh[64][DSTATE];
    const float* projb = proj + (size_t)b * LSEQ * 96;

    for (int l0 = 0; l0 < LSEQ; l0 += 64) {
        __syncthreads();
        // stage B/C for 64 timesteps: 64 rows x 32 cols, 8 elems per thread
        #pragma unroll
        for (int i = 0; i < 8; ++i) {
            const int f = i * 256 + threadIdx.x;   // 0..2047
            const int r = f >> 5;
            const int c = f & 31;
            const float v = projb[(size_t)(l0 + r) * 96 + 64 + c];
            if (c < DSTATE) Bsh[r][c] = v;
            else            Csh[r][c - DSTATE] = v;
        }
        __syncthreads();

        for (int l = l0; l < l0 + 64; ++l) {
            const size_t tok = (size_t)b * LSEQ + l;
            const float dt = xz[tok * NXZ + d];              // delta
            const float uu = u[tok * DINNER + d];
            const float zz = xz[tok * NXZ + DINNER + d];     // z
            const float du = dt * uu;
            const int lr = l - l0;
            float y = 0.f;
            #pragma unroll
            for (int n = 0; n < DSTATE; ++n) {
                const float dA = __expf(dt * Av[n]);
                h[n] = fmaf(h[n], dA, du * Bsh[lr][n]);
                y = fmaf(h[n], Csh[lr][n], y);
            }
            const float yt = fmaf(uu, Dval, y);
            xz[tok * NXZ + d] = yt * silu_f(zz);             // yg over delta
        }
    }
}

// ---------------------------------------------------------------------------
extern "C" void kernel_launch(void* const* d_in, const int* in_sizes, int n_in,
                              void* d_out, int out_size, void* d_ws, size_t ws_size,
                              hipStream_t stream)
{
    const float* x     = (const float*)d_in[0];
    const float* W_in  = (const float*)d_in[1];
    const float* cw    = (const float*)d_in[2];
    const float* cb    = (const float*)d_in[3];
    const float* W_xp  = (const float*)d_in[4];
    const float* W_dt  = (const float*)d_in[5];
    const float* b_dt  = (const float*)d_in[6];
    const float* A_log = (const float*)d_in[7];
    const float* Dp    = (const float*)d_in[8];
    const float* W_out = (const float*)d_in[9];
    float* out = (float*)d_out;

    // workspace layout (f32), total 8192*(4096+2048+96)*4 = 204.5 MB:
    float* xz    = (float*)d_ws;                    // MTOK * 4096  (u_pre|z -> delta|z -> yg|z)
    float* u     = xz + (size_t)MTOK * NXZ;         // MTOK * 2048
    float* proj  = u + (size_t)MTOK * DINNER;       // MTOK * 96

    // 1) xz = x @ W_in                      [8192,1024]@[1024,4096]
    sgemm128<0, false><<<dim3(64, 32), 256, 0, stream>>>(
        x, DMODEL, W_in, NXZ, xz, NXZ, NXZ, DMODEL, nullptr);

    // 2) u = silu(depthwise_conv(xz[:, :2048]) + conv_b)
    conv_silu_kernel<<<(MTOK * 512) / 256, 256, 0, stream>>>(xz, cw, cb, u);

    // 3) proj = u @ W_xproj                 [8192,2048]@[2048,96]
    sgemm128<0, true><<<dim3(64, 1), 256, 0, stream>>>(
        u, DINNER, W_xp, 96, proj, 96, 96, DINNER, nullptr);

    // 4) delta = softplus(proj[:, :64] @ W_dt + b_dt) -> xz[:, 0:2048] (u_pre is dead)
    sgemm128<1, false><<<dim3(64, 16), 256, 0, stream>>>(
        proj, 96, W_dt, DINNER, xz, NXZ, DINNER, DTRANK, b_dt);

    // 5) selective scan + skip + gate -> yg = xz[:, 0:2048] (over delta, in place)
    scan_kernel<<<dim3(8, 4), 256, 0, stream>>>(u, xz, proj, A_log, Dp, 0);

    // 6) out = yg @ W_out                   [8192,2048]@[2048,1024], A stride 4096
    sgemm128<0, false><<<dim3(64, 8), 256, 0, stream>>>(
        xz, NXZ, W_out, DMODEL, out, DMODEL, DMODEL, DINNER, nullptr);
}

// Round 4
// 1994.381 us; speedup vs baseline: 1.5940x; 1.5940x over previous
//
#include <hip/hip_runtime.h>
#include <hip/hip_bf16.h>
#include <math.h>

// Problem constants
#define MTOK   8192   // B*L
#define LSEQ   2048
#define NBATCH 4
#define DMODEL 1024
#define DINNER 2048
#define DSTATE 16
#define DTRANK 64
#define NXZ    4096   // 2*DINNER
#define CHUNK  64
#define NCH    32     // LSEQ / CHUNK

__device__ __forceinline__ float silu_f(float x) { return x / (1.f + __expf(-x)); }

// ---------------------------------------------------------------------------
// Generic f32 SGEMM: C[M,N] = A[M,K] @ B[K,N], row-major, strides lda/ldb/ldc.
// BM=BN=128, BK=8, 256 threads, each thread computes 2x2 blocks of 4x4.
// EPI: 0 = none, 1 = softplus(acc + bias[col])  (for delta)
// BN_GUARD: guard B loads / C stores against col >= N (N % 4 == 0 assumed).
// ---------------------------------------------------------------------------
template<int EPI, bool BN_GUARD>
__global__ __launch_bounds__(256)
void sgemm128(const float* __restrict__ A, int lda,
              const float* __restrict__ B, int ldb,
              float* __restrict__ C, int ldc,
              int N, int K, const float* __restrict__ bias)
{
    __shared__ float As[8][132];   // A tile, transposed: As[k][row]
    __shared__ float Bs[8][132];   // B tile: Bs[k][col]

    const int tid  = threadIdx.x;
    const int row0 = blockIdx.x * 128;
    const int col0 = blockIdx.y * 128;

    // staging indices
    const int arow = tid >> 1;            // 0..127
    const int acol = (tid & 1) << 2;      // 0 or 4
    const int brow = tid >> 5;            // 0..7
    const int bcol = (tid & 31) << 2;     // 0..124

    // compute indices
    const int tx = tid & 15;              // col group
    const int ty = tid >> 4;              // row group

    const float* Ag = A + (size_t)(row0 + arow) * lda + acol;
    const float* Bg = B + (size_t)brow * ldb + col0 + bcol;
    const bool bload_ok = !BN_GUARD || (col0 + bcol) < N;

    float acc[2][2][4][4] = {};

    for (int k0 = 0; k0 < K; k0 += 8) {
        float4 av = *(const float4*)(Ag + k0);
        float4 bv = make_float4(0.f, 0.f, 0.f, 0.f);
        if (bload_ok) bv = *(const float4*)(Bg + (size_t)k0 * ldb);

        As[acol + 0][arow] = av.x;
        As[acol + 1][arow] = av.y;
        As[acol + 2][arow] = av.z;
        As[acol + 3][arow] = av.w;
        *(float4*)&Bs[brow][bcol] = bv;
        __syncthreads();

        #pragma unroll
        for (int k = 0; k < 8; ++k) {
            const float4 a0 = *(const float4*)&As[k][ty * 4];
            const float4 a1 = *(const float4*)&As[k][64 + ty * 4];
            const float4 b0 = *(const float4*)&Bs[k][tx * 4];
            const float4 b1 = *(const float4*)&Bs[k][64 + tx * 4];
            const float ar[2][4] = {{a0.x, a0.y, a0.z, a0.w}, {a1.x, a1.y, a1.z, a1.w}};
            const float bc[2][4] = {{b0.x, b0.y, b0.z, b0.w}, {b1.x, b1.y, b1.z, b1.w}};
            #pragma unroll
            for (int i = 0; i < 2; ++i)
                #pragma unroll
                for (int j = 0; j < 2; ++j)
                    #pragma unroll
                    for (int r = 0; r < 4; ++r)
                        #pragma unroll
                        for (int c = 0; c < 4; ++c)
                            acc[i][j][r][c] = fmaf(ar[i][r], bc[j][c], acc[i][j][r][c]);
        }
        __syncthreads();
    }

    #pragma unroll
    for (int i = 0; i < 2; ++i) {
        #pragma unroll
        for (int j = 0; j < 2; ++j) {
            const int col = col0 + j * 64 + tx * 4;
            if (BN_GUARD && col >= N) continue;
            #pragma unroll
            for (int r = 0; r < 4; ++r) {
                const int row = row0 + i * 64 + ty * 4 + r;
                float4 v;
                float* vp = &v.x;
                #pragma unroll
                for (int c = 0; c < 4; ++c) {
                    float t = acc[i][j][r][c];
                    if (EPI == 1) {
                        t += bias[col + c];
                        t = (t > 20.f) ? t : log1pf(expf(t));  // softplus
                    }
                    vp[c] = t;
                }
                *(float4*)(C + (size_t)row * ldc + col) = v;
            }
        }
    }
}

// ---------------------------------------------------------------------------
// Causal depthwise conv (D_CONV=4) + bias + SiLU.
// ---------------------------------------------------------------------------
__global__ __launch_bounds__(256)
void conv_silu_kernel(const float* __restrict__ xz,
                      const float* __restrict__ cw,   // [DINNER][4]
                      const float* __restrict__ cb,   // [DINNER]
                      float* __restrict__ u)
{
    const int idx = blockIdx.x * 256 + threadIdx.x;   // [0, MTOK*512)
    const int d4  = idx & 511;
    const int ml  = idx >> 9;                         // b*LSEQ + l
    const int l   = ml & (LSEQ - 1);
    const int d   = d4 << 2;

    float wv[4][4];
    #pragma unroll
    for (int i = 0; i < 4; ++i) {
        const float4 w = *(const float4*)(cw + (size_t)(d + i) * 4);
        wv[i][0] = w.x; wv[i][1] = w.y; wv[i][2] = w.z; wv[i][3] = w.w;
    }

    float4 acc = *(const float4*)(cb + d);
    #pragma unroll
    for (int j = 0; j < 4; ++j) {
        const int ls = l - 3 + j;
        if (ls < 0) continue;
        const float4 xv = *(const float4*)(xz + (size_t)(ml - 3 + j) * NXZ + d);
        acc.x = fmaf(xv.x, wv[0][j], acc.x);
        acc.y = fmaf(xv.y, wv[1][j], acc.y);
        acc.z = fmaf(xv.z, wv[2][j], acc.z);
        acc.w = fmaf(xv.w, wv[3][j], acc.w);
    }
    acc.x = silu_f(acc.x);
    acc.y = silu_f(acc.y);
    acc.z = silu_f(acc.z);
    acc.w = silu_f(acc.w);
    *(float4*)(u + (size_t)ml * DINNER + d) = acc;
}

// ---------------------------------------------------------------------------
// Chunked selective scan.
// Recurrence per (b,d,n): h <- exp(dt*A[n])*h + dt*u*B[n]; y = sum_n h*C[n].
// Chunk transfer: h_out = exp(A*sum_dt)*h_in + S_local.
//
// pass1: per chunk, compute S_local[16] (h_in = 0) and sum_dt.
// pass2: per (b,d), serial over chunks: replace Sbuf[c] with h_in for chunk c.
// pass3: per chunk, re-run from true h_in, apply skip + gate, write yg.
//
// Layouts (d fastest for coalescing):
//   Sbuf [B][NCH][16][DINNER], sumdt [B][NCH][DINNER]
// ---------------------------------------------------------------------------
__global__ __launch_bounds__(256)
void scan_pass1(const float* __restrict__ u,
                const float* __restrict__ xz,     // delta in cols 0..2047
                const float* __restrict__ proj,   // [MTOK][96], cols 64..79 = B
                const float* __restrict__ A_log,  // [DINNER][16]
                float* __restrict__ Sbuf,
                float* __restrict__ sumdt)
{
    const int d = blockIdx.x * 256 + threadIdx.x;   // 0..2047
    const int c = blockIdx.y;                       // chunk
    const int b = blockIdx.z;

    float Av[DSTATE];
    #pragma unroll
    for (int n = 0; n < DSTATE; ++n)
        Av[n] = -__expf(A_log[(size_t)d * DSTATE + n]);

    __shared__ float Bsh[CHUNK][DSTATE];
    const float* projb = proj + ((size_t)b * LSEQ + (size_t)c * CHUNK) * 96;
    #pragma unroll
    for (int i = 0; i < (CHUNK * DSTATE) / 256; ++i) {   // 4
        const int f = i * 256 + threadIdx.x;
        const int r = f >> 4;
        const int col = f & 15;
        Bsh[r][col] = projb[(size_t)r * 96 + 64 + col];
    }
    __syncthreads();

    float S[DSTATE];
    #pragma unroll
    for (int n = 0; n < DSTATE; ++n) S[n] = 0.f;
    float sdt = 0.f;

    const size_t tok0 = (size_t)b * LSEQ + (size_t)c * CHUNK;
    for (int l = 0; l < CHUNK; ++l) {
        const float dt = xz[(tok0 + l) * NXZ + d];
        const float uu = u[(tok0 + l) * DINNER + d];
        sdt += dt;
        const float du = dt * uu;
        #pragma unroll
        for (int n = 0; n < DSTATE; ++n) {
            const float a = __expf(dt * Av[n]);
            S[n] = fmaf(S[n], a, du * Bsh[l][n]);
        }
    }

    const size_t base = (size_t)b * NCH + c;
    #pragma unroll
    for (int n = 0; n < DSTATE; ++n)
        Sbuf[(base * DSTATE + n) * DINNER + d] = S[n];
    sumdt[base * DINNER + d] = sdt;
}

__global__ __launch_bounds__(256)
void scan_pass2(const float* __restrict__ A_log,
                const float* __restrict__ sumdt,
                float* __restrict__ Sbuf)
{
    const int d = blockIdx.x * 256 + threadIdx.x;   // 0..2047
    const int b = blockIdx.y;

    float Av[DSTATE];
    #pragma unroll
    for (int n = 0; n < DSTATE; ++n)
        Av[n] = -__expf(A_log[(size_t)d * DSTATE + n]);

    float h[DSTATE];
    #pragma unroll
    for (int n = 0; n < DSTATE; ++n) h[n] = 0.f;

    for (int c = 0; c < NCH; ++c) {
        const size_t base = (size_t)b * NCH + c;
        const float sdt = sumdt[base * DINNER + d];
        #pragma unroll
        for (int n = 0; n < DSTATE; ++n) {
            const size_t idx = (base * DSTATE + n) * DINNER + d;
            const float tmp = Sbuf[idx];      // local S of chunk c
            Sbuf[idx] = h[n];                 // h_in for chunk c
            const float e = __expf(sdt * Av[n]);
            h[n] = fmaf(h[n], e, tmp);
        }
    }
}

__global__ __launch_bounds__(256)
void scan_pass3(const float* __restrict__ u,
                float* __restrict__ xz,           // delta|z; yg written over delta
                const float* __restrict__ proj,
                const float* __restrict__ A_log,
                const float* __restrict__ Dp,
                const float* __restrict__ Sbuf)   // holds h_in per chunk
{
    const int d = blockIdx.x * 256 + threadIdx.x;
    const int c = blockIdx.y;
    const int b = blockIdx.z;

    float Av[DSTATE];
    #pragma unroll
    for (int n = 0; n < DSTATE; ++n)
        Av[n] = -__expf(A_log[(size_t)d * DSTATE + n]);

    float h[DSTATE];
    const size_t base = (size_t)b * NCH + c;
    #pragma unroll
    for (int n = 0; n < DSTATE; ++n)
        h[n] = Sbuf[(base * DSTATE + n) * DINNER + d];

    const float Dval = Dp[d];

    __shared__ float Bsh[CHUNK][DSTATE];
    __shared__ float Csh[CHUNK][DSTATE];
    const float* projb = proj + ((size_t)b * LSEQ + (size_t)c * CHUNK) * 96;
    #pragma unroll
    for (int i = 0; i < (CHUNK * 2 * DSTATE) / 256; ++i) {   // 8
        const int f = i * 256 + threadIdx.x;
        const int r = f >> 5;
        const int col = f & 31;
        const float v = projb[(size_t)r * 96 + 64 + col];
        if (col < DSTATE) Bsh[r][col] = v;
        else              Csh[r][col - DSTATE] = v;
    }
    __syncthreads();

    const size_t tok0 = (size_t)b * LSEQ + (size_t)c * CHUNK;
    for (int l = 0; l < CHUNK; ++l) {
        const size_t tok = tok0 + l;
        const float dt = xz[tok * NXZ + d];
        const float uu = u[tok * DINNER + d];
        const float zz = xz[tok * NXZ + DINNER + d];
        const float du = dt * uu;
        float y = 0.f;
        #pragma unroll
        for (int n = 0; n < DSTATE; ++n) {
            const float a = __expf(dt * Av[n]);
            h[n] = fmaf(h[n], a, du * Bsh[l][n]);
            y = fmaf(h[n], Csh[l][n], y);
        }
        const float yt = fmaf(uu, Dval, y);
        xz[tok * NXZ + d] = yt * silu_f(zz);
    }
}

// ---------------------------------------------------------------------------
extern "C" void kernel_launch(void* const* d_in, const int* in_sizes, int n_in,
                              void* d_out, int out_size, void* d_ws, size_t ws_size,
                              hipStream_t stream)
{
    const float* x     = (const float*)d_in[0];
    const float* W_in  = (const float*)d_in[1];
    const float* cw    = (const float*)d_in[2];
    const float* cb    = (const float*)d_in[3];
    const float* W_xp  = (const float*)d_in[4];
    const float* W_dt  = (const float*)d_in[5];
    const float* b_dt  = (const float*)d_in[6];
    const float* A_log = (const float*)d_in[7];
    const float* Dp    = (const float*)d_in[8];
    const float* W_out = (const float*)d_in[9];
    float* out = (float*)d_out;

    // workspace layout (f32), total ~222 MB:
    float* xz    = (float*)d_ws;                    // MTOK*4096 (u_pre|z -> delta|z -> yg|z)
    float* u     = xz + (size_t)MTOK * NXZ;         // MTOK*2048
    float* proj  = u + (size_t)MTOK * DINNER;       // MTOK*96
    float* Sbuf  = proj + (size_t)MTOK * 96;        // B*NCH*16*DINNER = 4.19M
    float* sumdt = Sbuf + (size_t)NBATCH * NCH * DSTATE * DINNER;  // B*NCH*DINNER

    // 1) xz = x @ W_in                      [8192,1024]@[1024,4096]
    sgemm128<0, false><<<dim3(64, 32), 256, 0, stream>>>(
        x, DMODEL, W_in, NXZ, xz, NXZ, NXZ, DMODEL, nullptr);

    // 2) u = silu(depthwise_conv(xz[:, :2048]) + conv_b)
    conv_silu_kernel<<<(MTOK * 512) / 256, 256, 0, stream>>>(xz, cw, cb, u);

    // 3) proj = u @ W_xproj                 [8192,2048]@[2048,96]
    sgemm128<0, true><<<dim3(64, 1), 256, 0, stream>>>(
        u, DINNER, W_xp, 96, proj, 96, 96, DINNER, nullptr);

    // 4) delta = softplus(proj[:, :64] @ W_dt + b_dt) -> xz[:, 0:2048]
    sgemm128<1, false><<<dim3(64, 16), 256, 0, stream>>>(
        proj, 96, W_dt, DINNER, xz, NXZ, DINNER, DTRANK, b_dt);

    // 5) chunked selective scan + skip + gate -> yg = xz[:, 0:2048]
    scan_pass1<<<dim3(DINNER / 256, NCH, NBATCH), 256, 0, stream>>>(
        u, xz, proj, A_log, Sbuf, sumdt);
    scan_pass2<<<dim3(DINNER / 256, NBATCH), 256, 0, stream>>>(
        A_log, sumdt, Sbuf);
    scan_pass3<<<dim3(DINNER / 256, NCH, NBATCH), 256, 0, stream>>>(
        u, xz, proj, A_log, Dp, Sbuf);

    // 6) out = yg @ W_out                   [8192,2048]@[2048,1024], A stride 4096
    sgemm128<0, false><<<dim3(64, 8), 256, 0, stream>>>(
        xz, NXZ, W_out, DMODEL, out, DMODEL, DMODEL, DINNER, nullptr);
}

// Round 5
// 492.043 us; speedup vs baseline: 6.4610x; 4.0533x over previous
//
#include <hip/hip_runtime.h>
#include <hip/hip_bf16.h>
#include <math.h>

// Problem constants
#define MTOK   8192   // B*L
#define LSEQ   2048
#define NBATCH 4
#define DMODEL 1024
#define DINNER 2048
#define DSTATE 16
#define DTRANK 64
#define NXZ    4096
#define CHUNK  64
#define NCH    32     // LSEQ / CHUNK
#define NPROJ  (MTOK * 96)
#define SPLITK 8

typedef _Float16 f16;
using f16x8 = __attribute__((ext_vector_type(8))) _Float16;
using f16x4 = __attribute__((ext_vector_type(4))) _Float16;
using f32x4 = __attribute__((ext_vector_type(4))) float;

__device__ __forceinline__ float silu_f(float x) { return x / (1.f + __expf(-x)); }

// ---------------------------------------------------------------------------
// f32 -> f16 elementwise (vec4)
// ---------------------------------------------------------------------------
__global__ __launch_bounds__(256)
void cvt_f2h(const float* __restrict__ in, f16* __restrict__ out, int n4)
{
    const int i = blockIdx.x * 256 + threadIdx.x;
    if (i >= n4) return;
    const float4 v = ((const float4*)in)[i];
    f16x4 o;
    o[0] = (f16)v.x; o[1] = (f16)v.y; o[2] = (f16)v.z; o[3] = (f16)v.w;
    ((f16x4*)out)[i] = o;
}

// ---------------------------------------------------------------------------
// Transpose + convert: in f32 [R][C] -> out f16 [C][R].  Grid (C/32, R/32).
// ---------------------------------------------------------------------------
__global__ __launch_bounds__(256)
void tcvt(const float* __restrict__ in, f16* __restrict__ out, int R, int C)
{
    __shared__ float t[32][33];
    const int c0 = blockIdx.x * 32, r0 = blockIdx.y * 32;
    const int tx = threadIdx.x & 31, ty = threadIdx.x >> 5;   // 32 x 8
    #pragma unroll
    for (int j = 0; j < 4; ++j)
        t[ty + 8 * j][tx] = in[(size_t)(r0 + ty + 8 * j) * C + c0 + tx];
    __syncthreads();
    #pragma unroll
    for (int j = 0; j < 4; ++j)
        out[(size_t)(c0 + ty + 8 * j) * R + r0 + tx] = (f16)t[tx][ty + 8 * j];
}

// ---------------------------------------------------------------------------
// FP16 MFMA GEMM: C[M,N] = A[M,K] @ B[K,N], A f16 [M][K] (lda), B given
// TRANSPOSED as Bt f16 [N][K] (ldb).  Tile 128x128, BK=32, 4 waves (2x2),
// each wave 64x64 via 4x4 frags of mfma_f32_16x16x32_f16.
// Grid: (M/128, N/128) exact.  EPI: 0 none, 1 softplus(acc+bias[col]).
// ---------------------------------------------------------------------------
template<int EPI, typename OUT_T>
__global__ __launch_bounds__(256)
void hgemm128(const f16* __restrict__ A, int lda,
              const f16* __restrict__ Bt, int ldb,
              OUT_T* __restrict__ C, int ldc,
              int K, const float* __restrict__ bias)
{
    __shared__ __align__(16) f16 As[128][40];   // +8 pad: 80B pitch
    __shared__ __align__(16) f16 Bs[128][40];

    const int tid  = threadIdx.x;
    const int lane = tid & 63, wave = tid >> 6;
    const int wr = wave >> 1, wc = wave & 1;
    const int row0 = blockIdx.x * 128, col0 = blockIdx.y * 128;

    const int srow = tid >> 1, skoff = (tid & 1) * 16;
    const f16* Ag = A  + (size_t)(row0 + srow) * lda + skoff;
    const f16* Bg = Bt + (size_t)(col0 + srow) * ldb + skoff;

    const int frow = lane & 15, fk = (lane >> 4) * 8;

    f32x4 acc[4][4] = {};

    for (int k0 = 0; k0 < K; k0 += 32) {
        const f16x8 a0 = *(const f16x8*)(Ag + k0);
        const f16x8 a1 = *(const f16x8*)(Ag + k0 + 8);
        const f16x8 b0 = *(const f16x8*)(Bg + k0);
        const f16x8 b1 = *(const f16x8*)(Bg + k0 + 8);
        __syncthreads();
        *(f16x8*)&As[srow][skoff]     = a0;
        *(f16x8*)&As[srow][skoff + 8] = a1;
        *(f16x8*)&Bs[srow][skoff]     = b0;
        *(f16x8*)&Bs[srow][skoff + 8] = b1;
        __syncthreads();

        f16x8 af[4], bf[4];
        #pragma unroll
        for (int m = 0; m < 4; ++m)
            af[m] = *(const f16x8*)&As[wr * 64 + m * 16 + frow][fk];
        #pragma unroll
        for (int n = 0; n < 4; ++n)
            bf[n] = *(const f16x8*)&Bs[wc * 64 + n * 16 + frow][fk];
        #pragma unroll
        for (int m = 0; m < 4; ++m)
            #pragma unroll
            for (int n = 0; n < 4; ++n)
                acc[m][n] = __builtin_amdgcn_mfma_f32_16x16x32_f16(af[m], bf[n], acc[m][n], 0, 0, 0);
    }

    const int rbase = row0 + wr * 64 + (lane >> 4) * 4;
    const int cbase = col0 + wc * 64 + (lane & 15);
    #pragma unroll
    for (int m = 0; m < 4; ++m) {
        #pragma unroll
        for (int n = 0; n < 4; ++n) {
            const int col = cbase + n * 16;
            #pragma unroll
            for (int r = 0; r < 4; ++r) {
                const int row = rbase + m * 16 + r;
                float tv = acc[m][n][r];
                if (EPI == 1) {
                    tv += bias[col];
                    tv = (tv > 20.f) ? tv : log1pf(expf(tv));
                }
                C[(size_t)row * ldc + col] = (OUT_T)tv;
            }
        }
    }
}

// ---------------------------------------------------------------------------
// Narrow-N GEMM for proj: part[sk] = uh[rows][kseg] @ WxpT^T, N=96, split-K=8.
// Tile 128 rows x 96 cols, BK=32; 4 waves stacked (32 rows each), frags 2x6.
// ---------------------------------------------------------------------------
__global__ __launch_bounds__(256)
void hgemm_n96(const f16* __restrict__ A,      // uh [MTOK][DINNER]
               const f16* __restrict__ Bt,     // WxpT [96][DINNER]
               float* __restrict__ part)       // [SPLITK][MTOK][96]
{
    __shared__ __align__(16) f16 As[128][40];
    __shared__ __align__(16) f16 Bs[96][40];

    const int tid = threadIdx.x, lane = tid & 63, wave = tid >> 6;
    const int row0 = blockIdx.x * 128;
    const int sk = blockIdx.y;
    const int kbase = sk * (DINNER / SPLITK);   // 256

    const int srow = tid >> 1, skoff = (tid & 1) * 16;
    const f16* Ag = A  + (size_t)(row0 + srow) * DINNER + kbase + skoff;
    const f16* Bg = Bt + (size_t)srow * DINNER + kbase + skoff;

    const int frow = lane & 15, fk = (lane >> 4) * 8;

    f32x4 acc[2][6] = {};

    for (int kk = 0; kk < DINNER / SPLITK; kk += 32) {
        const f16x8 a0 = *(const f16x8*)(Ag + kk);
        const f16x8 a1 = *(const f16x8*)(Ag + kk + 8);
        f16x8 b0 = {}, b1 = {};
        if (tid < 192) { b0 = *(const f16x8*)(Bg + kk); b1 = *(const f16x8*)(Bg + kk + 8); }
        __syncthreads();
        *(f16x8*)&As[srow][skoff]     = a0;
        *(f16x8*)&As[srow][skoff + 8] = a1;
        if (tid < 192) {
            *(f16x8*)&Bs[srow][skoff]     = b0;
            *(f16x8*)&Bs[srow][skoff + 8] = b1;
        }
        __syncthreads();

        f16x8 af[2], bf[6];
        #pragma unroll
        for (int m = 0; m < 2; ++m)
            af[m] = *(const f16x8*)&As[wave * 32 + m * 16 + frow][fk];
        #pragma unroll
        for (int n = 0; n < 6; ++n)
            bf[n] = *(const f16x8*)&Bs[n * 16 + frow][fk];
        #pragma unroll
        for (int m = 0; m < 2; ++m)
            #pragma unroll
            for (int n = 0; n < 6; ++n)
                acc[m][n] = __builtin_amdgcn_mfma_f32_16x16x32_f16(af[m], bf[n], acc[m][n], 0, 0, 0);
    }

    #pragma unroll
    for (int m = 0; m < 2; ++m)
        #pragma unroll
        for (int n = 0; n < 6; ++n) {
            const int col = n * 16 + (lane & 15);
            #pragma unroll
            for (int r = 0; r < 4; ++r) {
                const int row = row0 + wave * 32 + m * 16 + (lane >> 4) * 4 + r;
                part[((size_t)sk * MTOK + row) * 96 + col] = acc[m][n][r];
            }
        }
}

__global__ __launch_bounds__(256)
void reduce3(const float* __restrict__ part, float* __restrict__ proj,
             f16* __restrict__ projh)
{
    const int e = blockIdx.x * 256 + threadIdx.x;   // < NPROJ
    float s = 0.f;
    #pragma unroll
    for (int i = 0; i < SPLITK; ++i) s += part[(size_t)i * NPROJ + e];
    proj[e]  = s;
    projh[e] = (f16)s;
}

// ---------------------------------------------------------------------------
// Causal depthwise conv (D_CONV=4) + bias + SiLU.  up f32 [MTOK][DINNER] dense
// -> uh f16 [MTOK][DINNER].
// ---------------------------------------------------------------------------
__global__ __launch_bounds__(256)
void conv_silu_kernel(const float* __restrict__ up,
                      const float* __restrict__ cw, const float* __restrict__ cb,
                      f16* __restrict__ uh)
{
    const int idx = blockIdx.x * 256 + threadIdx.x;   // MTOK*512
    const int d4  = idx & 511;
    const int ml  = idx >> 9;
    const int l   = ml & (LSEQ - 1);
    const int d   = d4 << 2;

    float wv[4][4];
    #pragma unroll
    for (int i = 0; i < 4; ++i) {
        const float4 w = *(const float4*)(cw + (size_t)(d + i) * 4);
        wv[i][0] = w.x; wv[i][1] = w.y; wv[i][2] = w.z; wv[i][3] = w.w;
    }

    float4 acc = *(const float4*)(cb + d);
    #pragma unroll
    for (int j = 0; j < 4; ++j) {
        const int ls = l - 3 + j;
        if (ls < 0) continue;
        const float4 xv = *(const float4*)(up + (size_t)(ml - 3 + j) * DINNER + d);
        acc.x = fmaf(xv.x, wv[0][j], acc.x);
        acc.y = fmaf(xv.y, wv[1][j], acc.y);
        acc.z = fmaf(xv.z, wv[2][j], acc.z);
        acc.w = fmaf(xv.w, wv[3][j], acc.w);
    }
    f16x4 o;
    o[0] = (f16)silu_f(acc.x);
    o[1] = (f16)silu_f(acc.y);
    o[2] = (f16)silu_f(acc.z);
    o[3] = (f16)silu_f(acc.w);
    *(f16x4*)(uh + (size_t)ml * DINNER + d) = o;
}

// ---------------------------------------------------------------------------
// Chunked selective scan (3 passes), dense layouts.
// ---------------------------------------------------------------------------
__global__ __launch_bounds__(256)
void scan_pass1(const f16* __restrict__ uh,
                const float* __restrict__ delta,   // [MTOK][DINNER]
                const float* __restrict__ proj,    // [MTOK][96], 64..95 = B,C
                const float* __restrict__ A_log,
                float* __restrict__ Sbuf, float* __restrict__ sumdt)
{
    const int d = blockIdx.x * 256 + threadIdx.x;
    const int c = blockIdx.y;
    const int b = blockIdx.z;

    float Av[DSTATE];
    #pragma unroll
    for (int n = 0; n < DSTATE; ++n)
        Av[n] = -__expf(A_log[(size_t)d * DSTATE + n]);

    __shared__ float Bsh[CHUNK][DSTATE];
    const float* projb = proj + ((size_t)b * LSEQ + (size_t)c * CHUNK) * 96;
    #pragma unroll
    for (int i = 0; i < (CHUNK * DSTATE) / 256; ++i) {
        const int f = i * 256 + threadIdx.x;
        Bsh[f >> 4][f & 15] = projb[(size_t)(f >> 4) * 96 + 64 + (f & 15)];
    }
    __syncthreads();

    float S[DSTATE];
    #pragma unroll
    for (int n = 0; n < DSTATE; ++n) S[n] = 0.f;
    float sdt = 0.f;

    const size_t tok0 = (size_t)b * LSEQ + (size_t)c * CHUNK;
    for (int l = 0; l < CHUNK; ++l) {
        const float dt = delta[(tok0 + l) * DINNER + d];
        const float uu = (float)uh[(tok0 + l) * DINNER + d];
        sdt += dt;
        const float du = dt * uu;
        #pragma unroll
        for (int n = 0; n < DSTATE; ++n) {
            const float a = __expf(dt * Av[n]);
            S[n] = fmaf(S[n], a, du * Bsh[l][n]);
        }
    }

    const size_t base = (size_t)b * NCH + c;
    #pragma unroll
    for (int n = 0; n < DSTATE; ++n)
        Sbuf[(base * DSTATE + n) * DINNER + d] = S[n];
    sumdt[base * DINNER + d] = sdt;
}

__global__ __launch_bounds__(256)
void scan_pass2(const float* __restrict__ A_log,
                const float* __restrict__ sumdt,
                float* __restrict__ Sbuf)
{
    const int d = blockIdx.x * 256 + threadIdx.x;
    const int b = blockIdx.y;

    float Av[DSTATE];
    #pragma unroll
    for (int n = 0; n < DSTATE; ++n)
        Av[n] = -__expf(A_log[(size_t)d * DSTATE + n]);

    float h[DSTATE];
    #pragma unroll
    for (int n = 0; n < DSTATE; ++n) h[n] = 0.f;

    for (int c = 0; c < NCH; ++c) {
        const size_t base = (size_t)b * NCH + c;
        const float sdt = sumdt[base * DINNER + d];
        #pragma unroll
        for (int n = 0; n < DSTATE; ++n) {
            const size_t idx = (base * DSTATE + n) * DINNER + d;
            const float tmp = Sbuf[idx];
            Sbuf[idx] = h[n];
            h[n] = fmaf(h[n], __expf(sdt * Av[n]), tmp);
        }
    }
}

__global__ __launch_bounds__(256)
void scan_pass3(const f16* __restrict__ uh,
                const float* __restrict__ delta,
                const f16* __restrict__ zh,
                const float* __restrict__ proj,
                const float* __restrict__ A_log,
                const float* __restrict__ Dp,
                const float* __restrict__ Sbuf,
                f16* __restrict__ ygh)
{
    const int d = blockIdx.x * 256 + threadIdx.x;
    const int c = blockIdx.y;
    const int b = blockIdx.z;

    float Av[DSTATE];
    #pragma unroll
    for (int n = 0; n < DSTATE; ++n)
        Av[n] = -__expf(A_log[(size_t)d * DSTATE + n]);

    float h[DSTATE];
    const size_t base = (size_t)b * NCH + c;
    #pragma unroll
    for (int n = 0; n < DSTATE; ++n)
        h[n] = Sbuf[(base * DSTATE + n) * DINNER + d];

    const float Dval = Dp[d];

    __shared__ float Bsh[CHUNK][DSTATE];
    __shared__ float Csh[CHUNK][DSTATE];
    const float* projb = proj + ((size_t)b * LSEQ + (size_t)c * CHUNK) * 96;
    #pragma unroll
    for (int i = 0; i < (CHUNK * 2 * DSTATE) / 256; ++i) {
        const int f = i * 256 + threadIdx.x;
        const int r = f >> 5, col = f & 31;
        const float v = projb[(size_t)r * 96 + 64 + col];
        if (col < DSTATE) Bsh[r][col] = v;
        else              Csh[r][col - DSTATE] = v;
    }
    __syncthreads();

    const size_t tok0 = (size_t)b * LSEQ + (size_t)c * CHUNK;
    for (int l = 0; l < CHUNK; ++l) {
        const size_t tok = tok0 + l;
        const float dt = delta[tok * DINNER + d];
        const float uu = (float)uh[tok * DINNER + d];
        const float zz = (float)zh[tok * DINNER + d];
        const float du = dt * uu;
        float y = 0.f;
        #pragma unroll
        for (int n = 0; n < DSTATE; ++n) {
            const float a = __expf(dt * Av[n]);
            h[n] = fmaf(h[n], a, du * Bsh[l][n]);
            y = fmaf(h[n], Csh[l][n], y);
        }
        const float yt = fmaf(uu, Dval, y);
        ygh[tok * DINNER + d] = (f16)(yt * silu_f(zz));
    }
}

// ---------------------------------------------------------------------------
extern "C" void kernel_launch(void* const* d_in, const int* in_sizes, int n_in,
                              void* d_out, int out_size, void* d_ws, size_t ws_size,
                              hipStream_t stream)
{
    const float* x     = (const float*)d_in[0];
    const float* W_in  = (const float*)d_in[1];
    const float* cw    = (const float*)d_in[2];
    const float* cb    = (const float*)d_in[3];
    const float* W_xp  = (const float*)d_in[4];
    const float* W_dt  = (const float*)d_in[5];
    const float* b_dt  = (const float*)d_in[6];
    const float* A_log = (const float*)d_in[7];
    const float* Dp    = (const float*)d_in[8];
    const float* W_out = (const float*)d_in[9];
    float* out = (float*)d_out;

    // ---- workspace layout, total 195.2 MB ----
    float* updelta = (float*)d_ws;                   // [MTOK][DINNER] f32: u_pre -> delta
    f16*   zh      = (f16*)(updelta + (size_t)MTOK * DINNER);   // [MTOK][DINNER] f16
    f16*   uh      = zh + (size_t)MTOK * DINNER;     // [MTOK][DINNER] f16 (xh alias at base)
    float* proj    = (float*)(uh + (size_t)MTOK * DINNER);      // [MTOK][96] f32
    f16*   projh   = (f16*)(proj + NPROJ);           // [MTOK][96] f16
    float* Sbuf    = (float*)(projh + NPROJ);        // [B][NCH][16][DINNER] f32
    float* sumdt   = Sbuf + (size_t)NBATCH * NCH * DSTATE * DINNER;
    f16*   WxpT    = (f16*)(sumdt + (size_t)NBATCH * NCH * DINNER);  // [96][DINNER]
    f16*   WdtT    = WxpT + (size_t)96 * DINNER;     // [DINNER][64]
    f16*   WoutT   = WdtT + (size_t)DINNER * DTRANK; // [DMODEL][DINNER]
    f16*   big     = WoutT + (size_t)DMODEL * DINNER;// 16.78M f16 alias region
    f16*   WinT    = big;                            // [NXZ][DMODEL] (phase 1)
    float* part3   = (float*)(big + (size_t)NXZ * DMODEL);  // [8][MTOK][96] (phase 2)
    f16*   ygh     = big;                            // [MTOK][DINNER] (phase 3)
    f16*   xh      = uh;                             // [MTOK][DMODEL] (pre-conv alias)

    // 1) convert x, transpose-convert W_in
    cvt_f2h<<<(MTOK * DMODEL / 4 + 255) / 256, 256, 0, stream>>>(x, xh, MTOK * DMODEL / 4);
    tcvt<<<dim3(NXZ / 32, DMODEL / 32), 256, 0, stream>>>(W_in, WinT, DMODEL, NXZ);

    // 2) GEMM1a: u_pre = x @ W_in[:, :2048]   (f32 out, dense)
    hgemm128<0, float><<<dim3(64, 16), 256, 0, stream>>>(
        xh, DMODEL, WinT, DMODEL, updelta, DINNER, DMODEL, nullptr);
    // 2b) GEMM1b: z = x @ W_in[:, 2048:]      (f16 out)
    hgemm128<0, f16><<<dim3(64, 16), 256, 0, stream>>>(
        xh, DMODEL, WinT + (size_t)DINNER * DMODEL, DMODEL, zh, DINNER, DMODEL, nullptr);

    // 3) conv + silu -> uh f16   (clobbers xh)
    conv_silu_kernel<<<(MTOK * 512) / 256, 256, 0, stream>>>(updelta, cw, cb, uh);

    // 4) proj = u @ W_xproj  (split-K=8, N=96) + reduce
    tcvt<<<dim3(96 / 32, DINNER / 32), 256, 0, stream>>>(W_xp, WxpT, DINNER, 96);
    hgemm_n96<<<dim3(64, SPLITK), 256, 0, stream>>>(uh, WxpT, part3);
    reduce3<<<NPROJ / 256, 256, 0, stream>>>(part3, proj, projh);

    // 5) delta = softplus(proj[:, :64] @ W_dt + b_dt) -> updelta (f32, over u_pre)
    tcvt<<<dim3(DINNER / 32, DTRANK / 32), 256, 0, stream>>>(W_dt, WdtT, DTRANK, DINNER);
    hgemm128<1, float><<<dim3(64, 16), 256, 0, stream>>>(
        projh, 96, WdtT, DTRANK, updelta, DINNER, DTRANK, b_dt);

    // 6) chunked scan + skip + gate -> ygh f16 (clobbers WinT/part3)
    scan_pass1<<<dim3(DINNER / 256, NCH, NBATCH), 256, 0, stream>>>(
        uh, updelta, proj, A_log, Sbuf, sumdt);
    scan_pass2<<<dim3(DINNER / 256, NBATCH), 256, 0, stream>>>(A_log, sumdt, Sbuf);
    scan_pass3<<<dim3(DINNER / 256, NCH, NBATCH), 256, 0, stream>>>(
        uh, updelta, zh, proj, A_log, Dp, Sbuf, ygh);

    // 7) out = yg @ W_out
    tcvt<<<dim3(DMODEL / 32, DINNER / 32), 256, 0, stream>>>(W_out, WoutT, DINNER, DMODEL);
    hgemm128<0, float><<<dim3(64, 8), 256, 0, stream>>>(
        ygh, DINNER, WoutT, DINNER, out, DMODEL, DINNER, nullptr);
}

// Round 6
// 433.540 us; speedup vs baseline: 7.3328x; 1.1349x over previous
//
#include <hip/hip_runtime.h>
#include <hip/hip_bf16.h>
#include <math.h>

// Problem constants
#define MTOK   8192   // B*L
#define LSEQ   2048
#define NBATCH 4
#define DMODEL 1024
#define DINNER 2048
#define DSTATE 16
#define DTRANK 64
#define NXZ    4096
#define CHUNK  64
#define NCH    32     // LSEQ / CHUNK
#define NPROJ  (MTOK * 96)
#define SPLITK 8

typedef _Float16 f16;
using f16x8 = __attribute__((ext_vector_type(8))) _Float16;
using f16x4 = __attribute__((ext_vector_type(4))) _Float16;
using f32x4 = __attribute__((ext_vector_type(4))) float;

__device__ __forceinline__ float silu_f(float x) { return x / (1.f + __expf(-x)); }

// async global->LDS, 16B per lane; lds dest = wave-uniform base + lane*16B
__device__ __forceinline__ void gload_lds16(const void* g, void* l) {
    __builtin_amdgcn_global_load_lds(
        (const __attribute__((address_space(1))) void*)g,
        (__attribute__((address_space(3))) void*)l, 16, 0, 0);
}

// ---------------------------------------------------------------------------
// f32 -> f16 elementwise (vec4)
// ---------------------------------------------------------------------------
__global__ __launch_bounds__(256)
void cvt_f2h(const float* __restrict__ in, f16* __restrict__ out, int n4)
{
    const int i = blockIdx.x * 256 + threadIdx.x;
    if (i >= n4) return;
    const float4 v = ((const float4*)in)[i];
    f16x4 o;
    o[0] = (f16)v.x; o[1] = (f16)v.y; o[2] = (f16)v.z; o[3] = (f16)v.w;
    ((f16x4*)out)[i] = o;
}

// ---------------------------------------------------------------------------
// Transpose + convert: in f32 [R][C] -> out f16 [C][R].  Grid (C/32, R/32).
// ---------------------------------------------------------------------------
__global__ __launch_bounds__(256)
void tcvt(const float* __restrict__ in, f16* __restrict__ out, int R, int C)
{
    __shared__ float t[32][33];
    const int c0 = blockIdx.x * 32, r0 = blockIdx.y * 32;
    const int tx = threadIdx.x & 31, ty = threadIdx.x >> 5;   // 32 x 8
    #pragma unroll
    for (int j = 0; j < 4; ++j)
        t[ty + 8 * j][tx] = in[(size_t)(r0 + ty + 8 * j) * C + c0 + tx];
    __syncthreads();
    #pragma unroll
    for (int j = 0; j < 4; ++j)
        out[(size_t)(c0 + ty + 8 * j) * R + r0 + tx] = (f16)t[tx][ty + 8 * j];
}

// ---------------------------------------------------------------------------
// FP16 MFMA GEMM with global_load_lds staging (m97 structure).
// C[M,N] = A[M,K] @ B[K,N]; A f16 [M][K] (lda), B TRANSPOSED f16 [N][K] (ldb).
// Tile 128x128, BK=32, 4 waves (2x2), each wave 64x64 (4x4 frags 16x16x32).
// LDS: linear [128][32] f16, double-buffered; one barrier per K-step.
// Grid (M/128, N/128) exact.  EPI: 0 none, 1 softplus(acc+bias[col]).
// ---------------------------------------------------------------------------
template<int EPI, typename OUT_T>
__global__ __launch_bounds__(256)
void hgemm128(const f16* __restrict__ A, int lda,
              const f16* __restrict__ Bt, int ldb,
              OUT_T* __restrict__ C, int ldc,
              int K, const float* __restrict__ bias)
{
    __shared__ __align__(16) f16 As[2][128 * 32];
    __shared__ __align__(16) f16 Bs[2][128 * 32];

    const int tid  = threadIdx.x;
    const int lane = tid & 63, wave = tid >> 6;
    const int wr = wave >> 1, wc = wave & 1;
    const int row0 = blockIdx.x * 128, col0 = blockIdx.y * 128;

    // staging: wave w covers rows [32w, 32w+32) in two 16-row rounds;
    // lane l -> row +(l>>2), col f16 (l&3)*8  (matches HW lane*16B fanout)
    const int lrow = lane >> 2, lcol = (lane & 3) * 8;
    const f16* Agw = A  + (size_t)(row0 + wave * 32 + lrow) * lda + lcol;
    const f16* Bgw = Bt + (size_t)(col0 + wave * 32 + lrow) * ldb + lcol;
    const int ldsbase = (wave * 32) * 32;   // elems

    const int frow = lane & 15, fk = (lane >> 4) * 8;
    const int nt = K / 32;

    f32x4 acc[4][4] = {};

    // prologue: stage tile 0 into buf 0
    #pragma unroll
    for (int r = 0; r < 2; ++r) {
        gload_lds16(Agw + (size_t)r * 16 * lda, &As[0][ldsbase + r * 16 * 32]);
        gload_lds16(Bgw + (size_t)r * 16 * ldb, &Bs[0][ldsbase + r * 16 * 32]);
    }

    int cur = 0;
    for (int kt = 0; kt < nt; ++kt) {
        __syncthreads();   // staged buf `cur` visible; prev reads of cur^1 done
        if (kt + 1 < nt) {
            const int k0 = (kt + 1) * 32;
            #pragma unroll
            for (int r = 0; r < 2; ++r) {
                gload_lds16(Agw + (size_t)r * 16 * lda + k0, &As[cur ^ 1][ldsbase + r * 16 * 32]);
                gload_lds16(Bgw + (size_t)r * 16 * ldb + k0, &Bs[cur ^ 1][ldsbase + r * 16 * 32]);
            }
        }
        f16x8 af[4], bf[4];
        #pragma unroll
        for (int m = 0; m < 4; ++m)
            af[m] = *(const f16x8*)&As[cur][(wr * 64 + m * 16 + frow) * 32 + fk];
        #pragma unroll
        for (int n = 0; n < 4; ++n)
            bf[n] = *(const f16x8*)&Bs[cur][(wc * 64 + n * 16 + frow) * 32 + fk];
        #pragma unroll
        for (int m = 0; m < 4; ++m)
            #pragma unroll
            for (int n = 0; n < 4; ++n)
                acc[m][n] = __builtin_amdgcn_mfma_f32_16x16x32_f16(af[m], bf[n], acc[m][n], 0, 0, 0);
        cur ^= 1;
    }

    const int rbase = row0 + wr * 64 + (lane >> 4) * 4;
    const int cbase = col0 + wc * 64 + (lane & 15);
    #pragma unroll
    for (int m = 0; m < 4; ++m) {
        #pragma unroll
        for (int n = 0; n < 4; ++n) {
            const int col = cbase + n * 16;
            #pragma unroll
            for (int r = 0; r < 4; ++r) {
                const int row = rbase + m * 16 + r;
                float tv = acc[m][n][r];
                if (EPI == 1) {
                    tv += bias[col];
                    tv = (tv > 20.f) ? tv : log1pf(expf(tv));
                }
                C[(size_t)row * ldc + col] = (OUT_T)tv;
            }
        }
    }
}

// ---------------------------------------------------------------------------
// Narrow-N GEMM for proj: part[sk] = uh[rows][kseg] @ WxpT^T, N=96, split-K=8.
// ---------------------------------------------------------------------------
__global__ __launch_bounds__(256)
void hgemm_n96(const f16* __restrict__ A,      // uh [MTOK][DINNER]
               const f16* __restrict__ Bt,     // WxpT [96][DINNER]
               float* __restrict__ part)       // [SPLITK][MTOK][96]
{
    __shared__ __align__(16) f16 As[128][40];
    __shared__ __align__(16) f16 Bs[96][40];

    const int tid = threadIdx.x, lane = tid & 63, wave = tid >> 6;
    const int row0 = blockIdx.x * 128;
    const int sk = blockIdx.y;
    const int kbase = sk * (DINNER / SPLITK);   // 256

    const int srow = tid >> 1, skoff = (tid & 1) * 16;
    const f16* Ag = A  + (size_t)(row0 + srow) * DINNER + kbase + skoff;
    const f16* Bg = Bt + (size_t)srow * DINNER + kbase + skoff;

    const int frow = lane & 15, fk = (lane >> 4) * 8;

    f32x4 acc[2][6] = {};

    for (int kk = 0; kk < DINNER / SPLITK; kk += 32) {
        const f16x8 a0 = *(const f16x8*)(Ag + kk);
        const f16x8 a1 = *(const f16x8*)(Ag + kk + 8);
        f16x8 b0 = {}, b1 = {};
        if (tid < 192) { b0 = *(const f16x8*)(Bg + kk); b1 = *(const f16x8*)(Bg + kk + 8); }
        __syncthreads();
        *(f16x8*)&As[srow][skoff]     = a0;
        *(f16x8*)&As[srow][skoff + 8] = a1;
        if (tid < 192) {
            *(f16x8*)&Bs[srow][skoff]     = b0;
            *(f16x8*)&Bs[srow][skoff + 8] = b1;
        }
        __syncthreads();

        f16x8 af[2], bf[6];
        #pragma unroll
        for (int m = 0; m < 2; ++m)
            af[m] = *(const f16x8*)&As[wave * 32 + m * 16 + frow][fk];
        #pragma unroll
        for (int n = 0; n < 6; ++n)
            bf[n] = *(const f16x8*)&Bs[n * 16 + frow][fk];
        #pragma unroll
        for (int m = 0; m < 2; ++m)
            #pragma unroll
            for (int n = 0; n < 6; ++n)
                acc[m][n] = __builtin_amdgcn_mfma_f32_16x16x32_f16(af[m], bf[n], acc[m][n], 0, 0, 0);
    }

    #pragma unroll
    for (int m = 0; m < 2; ++m)
        #pragma unroll
        for (int n = 0; n < 6; ++n) {
            const int col = n * 16 + (lane & 15);
            #pragma unroll
            for (int r = 0; r < 4; ++r) {
                const int row = row0 + wave * 32 + m * 16 + (lane >> 4) * 4 + r;
                part[((size_t)sk * MTOK + row) * 96 + col] = acc[m][n][r];
            }
        }
}

__global__ __launch_bounds__(256)
void reduce3(const float* __restrict__ part, float* __restrict__ proj,
             f16* __restrict__ projh)
{
    const int e = blockIdx.x * 256 + threadIdx.x;   // < NPROJ
    float s = 0.f;
    #pragma unroll
    for (int i = 0; i < SPLITK; ++i) s += part[(size_t)i * NPROJ + e];
    proj[e]  = s;
    projh[e] = (f16)s;
}

// ---------------------------------------------------------------------------
// Causal depthwise conv (D_CONV=4) + bias + SiLU.
// ---------------------------------------------------------------------------
__global__ __launch_bounds__(256)
void conv_silu_kernel(const float* __restrict__ up,
                      const float* __restrict__ cw, const float* __restrict__ cb,
                      f16* __restrict__ uh)
{
    const int idx = blockIdx.x * 256 + threadIdx.x;   // MTOK*512
    const int d4  = idx & 511;
    const int ml  = idx >> 9;
    const int l   = ml & (LSEQ - 1);
    const int d   = d4 << 2;

    float wv[4][4];
    #pragma unroll
    for (int i = 0; i < 4; ++i) {
        const float4 w = *(const float4*)(cw + (size_t)(d + i) * 4);
        wv[i][0] = w.x; wv[i][1] = w.y; wv[i][2] = w.z; wv[i][3] = w.w;
    }

    float4 acc = *(const float4*)(cb + d);
    #pragma unroll
    for (int j = 0; j < 4; ++j) {
        const int ls = l - 3 + j;
        if (ls < 0) continue;
        const float4 xv = *(const float4*)(up + (size_t)(ml - 3 + j) * DINNER + d);
        acc.x = fmaf(xv.x, wv[0][j], acc.x);
        acc.y = fmaf(xv.y, wv[1][j], acc.y);
        acc.z = fmaf(xv.z, wv[2][j], acc.z);
        acc.w = fmaf(xv.w, wv[3][j], acc.w);
    }
    f16x4 o;
    o[0] = (f16)silu_f(acc.x);
    o[1] = (f16)silu_f(acc.y);
    o[2] = (f16)silu_f(acc.z);
    o[3] = (f16)silu_f(acc.w);
    *(f16x4*)(uh + (size_t)ml * DINNER + d) = o;
}

// ---------------------------------------------------------------------------
// Chunked selective scan.  A-structure fast path: when A[d][n] = (n+1)*A[d][0]
// (true for this model: A = -[1..16]), exp(dt*A[n]) = e1^(n+1), e1=exp(dt*A0):
// 1 exp + 15 muls instead of 16 exps.  Runtime-checked, generic fallback.
// ---------------------------------------------------------------------------
__device__ __forceinline__ bool load_A(const float* __restrict__ A_log, int d,
                                       float* Av)
{
    #pragma unroll
    for (int n = 0; n < DSTATE; ++n)
        Av[n] = -__expf(A_log[(size_t)d * DSTATE + n]);
    bool p = true;
    #pragma unroll
    for (int n = 1; n < DSTATE; ++n) {
        const float r = Av[n] / Av[0];
        if (fabsf(r - (float)(n + 1)) > 1e-3f) p = false;
    }
    return p;
}

__global__ __launch_bounds__(256)
void scan_pass1(const f16* __restrict__ uh,
                const float* __restrict__ delta,   // [MTOK][DINNER]
                const float* __restrict__ proj,    // [MTOK][96], 64..95 = B,C
                const float* __restrict__ A_log,
                float* __restrict__ Sbuf, float* __restrict__ sumdt)
{
    const int d = blockIdx.x * 256 + threadIdx.x;
    const int c = blockIdx.y;
    const int b = blockIdx.z;

    float Av[DSTATE];
    const bool pw = load_A(A_log, d, Av);
    const float Av0 = Av[0];

    __shared__ float Bsh[CHUNK][DSTATE];
    const float* projb = proj + ((size_t)b * LSEQ + (size_t)c * CHUNK) * 96;
    #pragma unroll
    for (int i = 0; i < (CHUNK * DSTATE) / 256; ++i) {
        const int f = i * 256 + threadIdx.x;
        Bsh[f >> 4][f & 15] = projb[(size_t)(f >> 4) * 96 + 64 + (f & 15)];
    }
    __syncthreads();

    float S[DSTATE];
    #pragma unroll
    for (int n = 0; n < DSTATE; ++n) S[n] = 0.f;
    float sdt = 0.f;

    const size_t tok0 = (size_t)b * LSEQ + (size_t)c * CHUNK;
    if (pw) {
        for (int l = 0; l < CHUNK; ++l) {
            const float dt = delta[(tok0 + l) * DINNER + d];
            const float uu = (float)uh[(tok0 + l) * DINNER + d];
            sdt += dt;
            const float du = dt * uu;
            const float e1 = __expf(dt * Av0);
            float dA = 1.f;
            #pragma unroll
            for (int n = 0; n < DSTATE; ++n) {
                dA *= e1;
                S[n] = fmaf(S[n], dA, du * Bsh[l][n]);
            }
        }
    } else {
        for (int l = 0; l < CHUNK; ++l) {
            const float dt = delta[(tok0 + l) * DINNER + d];
            const float uu = (float)uh[(tok0 + l) * DINNER + d];
            sdt += dt;
            const float du = dt * uu;
            #pragma unroll
            for (int n = 0; n < DSTATE; ++n)
                S[n] = fmaf(S[n], __expf(dt * Av[n]), du * Bsh[l][n]);
        }
    }

    const size_t base = (size_t)b * NCH + c;
    #pragma unroll
    for (int n = 0; n < DSTATE; ++n)
        Sbuf[(base * DSTATE + n) * DINNER + d] = S[n];
    sumdt[base * DINNER + d] = sdt;
}

__global__ __launch_bounds__(256)
void scan_pass2(const float* __restrict__ A_log,
                const float* __restrict__ sumdt,
                float* __restrict__ Sbuf)
{
    const int d = blockIdx.x * 256 + threadIdx.x;
    const int b = blockIdx.y;

    float Av[DSTATE];
    const bool pw = load_A(A_log, d, Av);
    const float Av0 = Av[0];

    float h[DSTATE];
    #pragma unroll
    for (int n = 0; n < DSTATE; ++n) h[n] = 0.f;

    for (int c = 0; c < NCH; ++c) {
        const size_t base = (size_t)b * NCH + c;
        const float sdt = sumdt[base * DINNER + d];
        if (pw) {
            const float e1 = __expf(sdt * Av0);
            float dA = 1.f;
            #pragma unroll
            for (int n = 0; n < DSTATE; ++n) {
                dA *= e1;
                const size_t idx = (base * DSTATE + n) * DINNER + d;
                const float tmp = Sbuf[idx];
                Sbuf[idx] = h[n];
                h[n] = fmaf(h[n], dA, tmp);
            }
        } else {
            #pragma unroll
            for (int n = 0; n < DSTATE; ++n) {
                const size_t idx = (base * DSTATE + n) * DINNER + d;
                const float tmp = Sbuf[idx];
                Sbuf[idx] = h[n];
                h[n] = fmaf(h[n], __expf(sdt * Av[n]), tmp);
            }
        }
    }
}

__global__ __launch_bounds__(256)
void scan_pass3(const f16* __restrict__ uh,
                const float* __restrict__ delta,
                const f16* __restrict__ zh,
                const float* __restrict__ proj,
                const float* __restrict__ A_log,
                const float* __restrict__ Dp,
                const float* __restrict__ Sbuf,
                f16* __restrict__ ygh)
{
    const int d = blockIdx.x * 256 + threadIdx.x;
    const int c = blockIdx.y;
    const int b = blockIdx.z;

    float Av[DSTATE];
    const bool pw = load_A(A_log, d, Av);
    const float Av0 = Av[0];

    float h[DSTATE];
    const size_t base = (size_t)b * NCH + c;
    #pragma unroll
    for (int n = 0; n < DSTATE; ++n)
        h[n] = Sbuf[(base * DSTATE + n) * DINNER + d];

    const float Dval = Dp[d];

    __shared__ float Bsh[CHUNK][DSTATE];
    __shared__ float Csh[CHUNK][DSTATE];
    const float* projb = proj + ((size_t)b * LSEQ + (size_t)c * CHUNK) * 96;
    #pragma unroll
    for (int i = 0; i < (CHUNK * 2 * DSTATE) / 256; ++i) {
        const int f = i * 256 + threadIdx.x;
        const int r = f >> 5, col = f & 31;
        const float v = projb[(size_t)r * 96 + 64 + col];
        if (col < DSTATE) Bsh[r][col] = v;
        else              Csh[r][col - DSTATE] = v;
    }
    __syncthreads();

    const size_t tok0 = (size_t)b * LSEQ + (size_t)c * CHUNK;
    for (int l = 0; l < CHUNK; ++l) {
        const size_t tok = tok0 + l;
        const float dt = delta[tok * DINNER + d];
        const float uu = (float)uh[tok * DINNER + d];
        const float zz = (float)zh[tok * DINNER + d];
        const float du = dt * uu;
        float y = 0.f;
        if (pw) {
            const float e1 = __expf(dt * Av0);
            float dA = 1.f;
            #pragma unroll
            for (int n = 0; n < DSTATE; ++n) {
                dA *= e1;
                h[n] = fmaf(h[n], dA, du * Bsh[l][n]);
                y = fmaf(h[n], Csh[l][n], y);
            }
        } else {
            #pragma unroll
            for (int n = 0; n < DSTATE; ++n) {
                h[n] = fmaf(h[n], __expf(dt * Av[n]), du * Bsh[l][n]);
                y = fmaf(h[n], Csh[l][n], y);
            }
        }
        const float yt = fmaf(uu, Dval, y);
        ygh[tok * DINNER + d] = (f16)(yt * silu_f(zz));
    }
}

// ---------------------------------------------------------------------------
extern "C" void kernel_launch(void* const* d_in, const int* in_sizes, int n_in,
                              void* d_out, int out_size, void* d_ws, size_t ws_size,
                              hipStream_t stream)
{
    const float* x     = (const float*)d_in[0];
    const float* W_in  = (const float*)d_in[1];
    const float* cw    = (const float*)d_in[2];
    const float* cb    = (const float*)d_in[3];
    const float* W_xp  = (const float*)d_in[4];
    const float* W_dt  = (const float*)d_in[5];
    const float* b_dt  = (const float*)d_in[6];
    const float* A_log = (const float*)d_in[7];
    const float* Dp    = (const float*)d_in[8];
    const float* W_out = (const float*)d_in[9];
    float* out = (float*)d_out;

    // ---- workspace layout, total 195.2 MB ----
    float* updelta = (float*)d_ws;                   // [MTOK][DINNER] f32: u_pre -> delta
    f16*   zh      = (f16*)(updelta + (size_t)MTOK * DINNER);   // [MTOK][DINNER] f16
    f16*   uh      = zh + (size_t)MTOK * DINNER;     // [MTOK][DINNER] f16 (xh alias at base)
    float* proj    = (float*)(uh + (size_t)MTOK * DINNER);      // [MTOK][96] f32
    f16*   projh   = (f16*)(proj + NPROJ);           // [MTOK][96] f16
    float* Sbuf    = (float*)(projh + NPROJ);        // [B][NCH][16][DINNER] f32
    float* sumdt   = Sbuf + (size_t)NBATCH * NCH * DSTATE * DINNER;
    f16*   WxpT    = (f16*)(sumdt + (size_t)NBATCH * NCH * DINNER);  // [96][DINNER]
    f16*   WdtT    = WxpT + (size_t)96 * DINNER;     // [DINNER][64]
    f16*   WoutT   = WdtT + (size_t)DINNER * DTRANK; // [DMODEL][DINNER]
    f16*   big     = WoutT + (size_t)DMODEL * DINNER;// 16.78M f16 alias region
    f16*   WinT    = big;                            // [NXZ][DMODEL] (phase 1)
    float* part3   = (float*)(big + (size_t)NXZ * DMODEL);  // [8][MTOK][96] (phase 2)
    f16*   ygh     = big;                            // [MTOK][DINNER] (phase 3)
    f16*   xh      = uh;                             // [MTOK][DMODEL] (pre-conv alias)

    // 1) convert x, transpose-convert W_in
    cvt_f2h<<<(MTOK * DMODEL / 4 + 255) / 256, 256, 0, stream>>>(x, xh, MTOK * DMODEL / 4);
    tcvt<<<dim3(NXZ / 32, DMODEL / 32), 256, 0, stream>>>(W_in, WinT, DMODEL, NXZ);

    // 2) GEMM1a: u_pre = x @ W_in[:, :2048]   (f32 out, dense)
    hgemm128<0, float><<<dim3(64, 16), 256, 0, stream>>>(
        xh, DMODEL, WinT, DMODEL, updelta, DINNER, DMODEL, nullptr);
    // 2b) GEMM1b: z = x @ W_in[:, 2048:]      (f16 out)
    hgemm128<0, f16><<<dim3(64, 16), 256, 0, stream>>>(
        xh, DMODEL, WinT + (size_t)DINNER * DMODEL, DMODEL, zh, DINNER, DMODEL, nullptr);

    // 3) conv + silu -> uh f16   (clobbers xh)
    conv_silu_kernel<<<(MTOK * 512) / 256, 256, 0, stream>>>(updelta, cw, cb, uh);

    // 4) proj = u @ W_xproj  (split-K=8, N=96) + reduce
    tcvt<<<dim3(96 / 32, DINNER / 32), 256, 0, stream>>>(W_xp, WxpT, DINNER, 96);
    hgemm_n96<<<dim3(64, SPLITK), 256, 0, stream>>>(uh, WxpT, part3);
    reduce3<<<NPROJ / 256, 256, 0, stream>>>(part3, proj, projh);

    // 5) delta = softplus(proj[:, :64] @ W_dt + b_dt) -> updelta (f32, over u_pre)
    tcvt<<<dim3(DINNER / 32, DTRANK / 32), 256, 0, stream>>>(W_dt, WdtT, DTRANK, DINNER);
    hgemm128<1, float><<<dim3(64, 16), 256, 0, stream>>>(
        projh, 96, WdtT, DTRANK, updelta, DINNER, DTRANK, b_dt);

    // 6) chunked scan + skip + gate -> ygh f16 (clobbers WinT/part3)
    scan_pass1<<<dim3(DINNER / 256, NCH, NBATCH), 256, 0, stream>>>(
        uh, updelta, proj, A_log, Sbuf, sumdt);
    scan_pass2<<<dim3(DINNER / 256, NBATCH), 256, 0, stream>>>(A_log, sumdt, Sbuf);
    scan_pass3<<<dim3(DINNER / 256, NCH, NBATCH), 256, 0, stream>>>(
        uh, updelta, zh, proj, A_log, Dp, Sbuf, ygh);

    // 7) out = yg @ W_out
    tcvt<<<dim3(DMODEL / 32, DINNER / 32), 256, 0, stream>>>(W_out, WoutT, DINNER, DMODEL);
    hgemm128<0, float><<<dim3(64, 8), 256, 0, stream>>>(
        ygh, DINNER, WoutT, DINNER, out, DMODEL, DINNER, nullptr);
}

// Round 7
// 382.102 us; speedup vs baseline: 8.3200x; 1.1346x over previous
//
#include <hip/hip_runtime.h>
#include <hip/hip_bf16.h>
#include <math.h>

// Problem constants
#define MTOK   8192   // B*L
#define LSEQ   2048
#define NBATCH 4
#define DMODEL 1024
#define DINNER 2048
#define DSTATE 16
#define DTRANK 64
#define NXZ    4096
#define CHUNK  64
#define NCH    32     // LSEQ / CHUNK
#define NPROJ  (MTOK * 96)
#define SPLITK 8

typedef _Float16 f16;
using f16x8 = __attribute__((ext_vector_type(8))) _Float16;
using f16x4 = __attribute__((ext_vector_type(4))) _Float16;
using f32x4 = __attribute__((ext_vector_type(4))) float;

__device__ __forceinline__ float silu_f(float x) { return x / (1.f + __expf(-x)); }

// async global->LDS, 16B per lane; lds dest = wave-uniform base + lane*16B
__device__ __forceinline__ void gload_lds16(const void* g, void* l) {
    __builtin_amdgcn_global_load_lds(
        (const __attribute__((address_space(1))) void*)g,
        (__attribute__((address_space(3))) void*)l, 16, 0, 0);
}

// ---------------------------------------------------------------------------
// f32 -> f16 elementwise (vec4)
// ---------------------------------------------------------------------------
__global__ __launch_bounds__(256)
void cvt_f2h(const float* __restrict__ in, f16* __restrict__ out, int n4)
{
    const int i = blockIdx.x * 256 + threadIdx.x;
    if (i >= n4) return;
    const float4 v = ((const float4*)in)[i];
    f16x4 o;
    o[0] = (f16)v.x; o[1] = (f16)v.y; o[2] = (f16)v.z; o[3] = (f16)v.w;
    ((f16x4*)out)[i] = o;
}

// ---------------------------------------------------------------------------
// Transpose + convert: in f32 [R][C] -> out f16 [C][R].  Grid (C/32, R/32).
// ---------------------------------------------------------------------------
__global__ __launch_bounds__(256)
void tcvt(const float* __restrict__ in, f16* __restrict__ out, int R, int C)
{
    __shared__ float t[32][33];
    const int c0 = blockIdx.x * 32, r0 = blockIdx.y * 32;
    const int tx = threadIdx.x & 31, ty = threadIdx.x >> 5;   // 32 x 8
    #pragma unroll
    for (int j = 0; j < 4; ++j)
        t[ty + 8 * j][tx] = in[(size_t)(r0 + ty + 8 * j) * C + c0 + tx];
    __syncthreads();
    #pragma unroll
    for (int j = 0; j < 4; ++j)
        out[(size_t)(c0 + ty + 8 * j) * R + r0 + tx] = (f16)t[tx][ty + 8 * j];
}

// ---------------------------------------------------------------------------
// FP16 MFMA GEMM with global_load_lds staging (m97 structure).
// C[M,N] = A[M,K] @ B[K,N]; A f16 [M][K] (lda), B TRANSPOSED f16 [N][K] (ldb).
// Tile 128x128, BK=32, 4 waves (2x2), each wave 64x64 (4x4 frags 16x16x32).
// LDS: linear [128][32] f16, double-buffered; one barrier per K-step.
// Grid (M/128, N/128) exact.  EPI: 0 none, 1 fast-softplus(acc+bias[col]).
// ---------------------------------------------------------------------------
template<int EPI, typename OUT_T>
__global__ __launch_bounds__(256)
void hgemm128(const f16* __restrict__ A, int lda,
              const f16* __restrict__ Bt, int ldb,
              OUT_T* __restrict__ C, int ldc,
              int K, const float* __restrict__ bias)
{
    __shared__ __align__(16) f16 As[2][128 * 32];
    __shared__ __align__(16) f16 Bs[2][128 * 32];

    const int tid  = threadIdx.x;
    const int lane = tid & 63, wave = tid >> 6;
    const int wr = wave >> 1, wc = wave & 1;
    const int row0 = blockIdx.x * 128, col0 = blockIdx.y * 128;

    // staging: wave w covers rows [32w, 32w+32) in two 16-row rounds;
    // lane l -> row +(l>>2), col f16 (l&3)*8  (matches HW lane*16B fanout)
    const int lrow = lane >> 2, lcol = (lane & 3) * 8;
    const f16* Agw = A  + (size_t)(row0 + wave * 32 + lrow) * lda + lcol;
    const f16* Bgw = Bt + (size_t)(col0 + wave * 32 + lrow) * ldb + lcol;
    const int ldsbase = (wave * 32) * 32;   // elems

    const int frow = lane & 15, fk = (lane >> 4) * 8;
    const int nt = K / 32;

    f32x4 acc[4][4] = {};

    // prologue: stage tile 0 into buf 0
    #pragma unroll
    for (int r = 0; r < 2; ++r) {
        gload_lds16(Agw + (size_t)r * 16 * lda, &As[0][ldsbase + r * 16 * 32]);
        gload_lds16(Bgw + (size_t)r * 16 * ldb, &Bs[0][ldsbase + r * 16 * 32]);
    }

    int cur = 0;
    for (int kt = 0; kt < nt; ++kt) {
        __syncthreads();   // staged buf `cur` visible; prev reads of cur^1 done
        if (kt + 1 < nt) {
            const int k0 = (kt + 1) * 32;
            #pragma unroll
            for (int r = 0; r < 2; ++r) {
                gload_lds16(Agw + (size_t)r * 16 * lda + k0, &As[cur ^ 1][ldsbase + r * 16 * 32]);
                gload_lds16(Bgw + (size_t)r * 16 * ldb + k0, &Bs[cur ^ 1][ldsbase + r * 16 * 32]);
            }
        }
        f16x8 af[4], bf[4];
        #pragma unroll
        for (int m = 0; m < 4; ++m)
            af[m] = *(const f16x8*)&As[cur][(wr * 64 + m * 16 + frow) * 32 + fk];
        #pragma unroll
        for (int n = 0; n < 4; ++n)
            bf[n] = *(const f16x8*)&Bs[cur][(wc * 64 + n * 16 + frow) * 32 + fk];
        #pragma unroll
        for (int m = 0; m < 4; ++m)
            #pragma unroll
            for (int n = 0; n < 4; ++n)
                acc[m][n] = __builtin_amdgcn_mfma_f32_16x16x32_f16(af[m], bf[n], acc[m][n], 0, 0, 0);
        cur ^= 1;
    }

    const int rbase = row0 + wr * 64 + (lane >> 4) * 4;
    const int cbase = col0 + wc * 64 + (lane & 15);
    #pragma unroll
    for (int m = 0; m < 4; ++m) {
        #pragma unroll
        for (int n = 0; n < 4; ++n) {
            const int col = cbase + n * 16;
            #pragma unroll
            for (int r = 0; r < 4; ++r) {
                const int row = rbase + m * 16 + r;
                float tv = acc[m][n][r];
                if (EPI == 1) {
                    tv += bias[col];
                    // fast softplus: hw trans ops; abs err <= ~6e-8 vs log1pf(expf)
                    tv = (tv > 20.f) ? tv : __logf(1.f + __expf(tv));
                }
                C[(size_t)row * ldc + col] = (OUT_T)tv;
            }
        }
    }
}

// ---------------------------------------------------------------------------
// Narrow-N GEMM for proj: part[sk] = uh[rows][kseg] @ WxpT^T, N=96, split-K=8.
// ---------------------------------------------------------------------------
__global__ __launch_bounds__(256)
void hgemm_n96(const f16* __restrict__ A,      // uh [MTOK][DINNER]
               const f16* __restrict__ Bt,     // WxpT [96][DINNER]
               float* __restrict__ part)       // [SPLITK][MTOK][96]
{
    __shared__ __align__(16) f16 As[128][40];
    __shared__ __align__(16) f16 Bs[96][40];

    const int tid = threadIdx.x, lane = tid & 63, wave = tid >> 6;
    const int row0 = blockIdx.x * 128;
    const int sk = blockIdx.y;
    const int kbase = sk * (DINNER / SPLITK);   // 256

    const int srow = tid >> 1, skoff = (tid & 1) * 16;
    const f16* Ag = A  + (size_t)(row0 + srow) * DINNER + kbase + skoff;
    const f16* Bg = Bt + (size_t)srow * DINNER + kbase + skoff;

    const int frow = lane & 15, fk = (lane >> 4) * 8;

    f32x4 acc[2][6] = {};

    for (int kk = 0; kk < DINNER / SPLITK; kk += 32) {
        const f16x8 a0 = *(const f16x8*)(Ag + kk);
        const f16x8 a1 = *(const f16x8*)(Ag + kk + 8);
        f16x8 b0 = {}, b1 = {};
        if (tid < 192) { b0 = *(const f16x8*)(Bg + kk); b1 = *(const f16x8*)(Bg + kk + 8); }
        __syncthreads();
        *(f16x8*)&As[srow][skoff]     = a0;
        *(f16x8*)&As[srow][skoff + 8] = a1;
        if (tid < 192) {
            *(f16x8*)&Bs[srow][skoff]     = b0;
            *(f16x8*)&Bs[srow][skoff + 8] = b1;
        }
        __syncthreads();

        f16x8 af[2], bf[6];
        #pragma unroll
        for (int m = 0; m < 2; ++m)
            af[m] = *(const f16x8*)&As[wave * 32 + m * 16 + frow][fk];
        #pragma unroll
        for (int n = 0; n < 6; ++n)
            bf[n] = *(const f16x8*)&Bs[n * 16 + frow][fk];
        #pragma unroll
        for (int m = 0; m < 2; ++m)
            #pragma unroll
            for (int n = 0; n < 6; ++n)
                acc[m][n] = __builtin_amdgcn_mfma_f32_16x16x32_f16(af[m], bf[n], acc[m][n], 0, 0, 0);
    }

    #pragma unroll
    for (int m = 0; m < 2; ++m)
        #pragma unroll
        for (int n = 0; n < 6; ++n) {
            const int col = n * 16 + (lane & 15);
            #pragma unroll
            for (int r = 0; r < 4; ++r) {
                const int row = row0 + wave * 32 + m * 16 + (lane >> 4) * 4 + r;
                part[((size_t)sk * MTOK + row) * 96 + col] = acc[m][n][r];
            }
        }
}

__global__ __launch_bounds__(256)
void reduce3(const float* __restrict__ part, float* __restrict__ proj,
             f16* __restrict__ projh)
{
    const int e = blockIdx.x * 256 + threadIdx.x;   // < NPROJ
    float s = 0.f;
    #pragma unroll
    for (int i = 0; i < SPLITK; ++i) s += part[(size_t)i * NPROJ + e];
    proj[e]  = s;
    projh[e] = (f16)s;
}

// ---------------------------------------------------------------------------
// Causal depthwise conv (D_CONV=4) + bias + SiLU.  uph f16 -> uh f16.
// ---------------------------------------------------------------------------
__global__ __launch_bounds__(256)
void conv_silu_kernel(const f16* __restrict__ uph,
                      const float* __restrict__ cw, const float* __restrict__ cb,
                      f16* __restrict__ uh)
{
    const int idx = blockIdx.x * 256 + threadIdx.x;   // MTOK*512
    const int d4  = idx & 511;
    const int ml  = idx >> 9;
    const int l   = ml & (LSEQ - 1);
    const int d   = d4 << 2;

    float wv[4][4];
    #pragma unroll
    for (int i = 0; i < 4; ++i) {
        const float4 w = *(const float4*)(cw + (size_t)(d + i) * 4);
        wv[i][0] = w.x; wv[i][1] = w.y; wv[i][2] = w.z; wv[i][3] = w.w;
    }

    float a0 = cb[d], a1 = cb[d + 1], a2 = cb[d + 2], a3 = cb[d + 3];
    #pragma unroll
    for (int j = 0; j < 4; ++j) {
        const int ls = l - 3 + j;
        if (ls < 0) continue;
        const f16x4 xv = *(const f16x4*)(uph + (size_t)(ml - 3 + j) * DINNER + d);
        a0 = fmaf((float)xv[0], wv[0][j], a0);
        a1 = fmaf((float)xv[1], wv[1][j], a1);
        a2 = fmaf((float)xv[2], wv[2][j], a2);
        a3 = fmaf((float)xv[3], wv[3][j], a3);
    }
    f16x4 o;
    o[0] = (f16)silu_f(a0);
    o[1] = (f16)silu_f(a1);
    o[2] = (f16)silu_f(a2);
    o[3] = (f16)silu_f(a3);
    *(f16x4*)(uh + (size_t)ml * DINNER + d) = o;
}

// ---------------------------------------------------------------------------
// Chunked selective scan.  A-structure fast path: when A[d][n] = (n+1)*A[d][0]
// (true here: A = -[1..16]), exp(dt*A[n]) = e1^(n+1), e1=exp(dt*A0):
// 1 exp + 15 muls instead of 16 exps.  Runtime-checked, generic fallback.
// ---------------------------------------------------------------------------
__device__ __forceinline__ bool load_A(const float* __restrict__ A_log, int d,
                                       float* Av)
{
    #pragma unroll
    for (int n = 0; n < DSTATE; ++n)
        Av[n] = -__expf(A_log[(size_t)d * DSTATE + n]);
    bool p = true;
    #pragma unroll
    for (int n = 1; n < DSTATE; ++n) {
        const float r = Av[n] / Av[0];
        if (fabsf(r - (float)(n + 1)) > 1e-3f) p = false;
    }
    return p;
}

__global__ __launch_bounds__(256)
void scan_pass1(const f16* __restrict__ uh,
                const float* __restrict__ delta,   // [MTOK][DINNER]
                const float* __restrict__ proj,    // [MTOK][96], 64..95 = B,C
                const float* __restrict__ A_log,
                float* __restrict__ Sbuf, float* __restrict__ sumdt)
{
    const int d = blockIdx.x * 256 + threadIdx.x;
    const int c = blockIdx.y;
    const int b = blockIdx.z;

    float Av[DSTATE];
    const bool pw = load_A(A_log, d, Av);
    const float Av0 = Av[0];

    __shared__ float Bsh[CHUNK][DSTATE];
    const float* projb = proj + ((size_t)b * LSEQ + (size_t)c * CHUNK) * 96;
    #pragma unroll
    for (int i = 0; i < (CHUNK * DSTATE) / 256; ++i) {
        const int f = i * 256 + threadIdx.x;
        Bsh[f >> 4][f & 15] = projb[(size_t)(f >> 4) * 96 + 64 + (f & 15)];
    }
    __syncthreads();

    float S[DSTATE];
    #pragma unroll
    for (int n = 0; n < DSTATE; ++n) S[n] = 0.f;
    float sdt = 0.f;

    const size_t tok0 = (size_t)b * LSEQ + (size_t)c * CHUNK;
    if (pw) {
        for (int l = 0; l < CHUNK; ++l) {
            const float dt = delta[(tok0 + l) * DINNER + d];
            const float uu = (float)uh[(tok0 + l) * DINNER + d];
            sdt += dt;
            const float du = dt * uu;
            const float e1 = __expf(dt * Av0);
            float dA = 1.f;
            #pragma unroll
            for (int n = 0; n < DSTATE; ++n) {
                dA *= e1;
                S[n] = fmaf(S[n], dA, du * Bsh[l][n]);
            }
        }
    } else {
        for (int l = 0; l < CHUNK; ++l) {
            const float dt = delta[(tok0 + l) * DINNER + d];
            const float uu = (float)uh[(tok0 + l) * DINNER + d];
            sdt += dt;
            const float du = dt * uu;
            #pragma unroll
            for (int n = 0; n < DSTATE; ++n)
                S[n] = fmaf(S[n], __expf(dt * Av[n]), du * Bsh[l][n]);
        }
    }

    const size_t base = (size_t)b * NCH + c;
    #pragma unroll
    for (int n = 0; n < DSTATE; ++n)
        Sbuf[(base * DSTATE + n) * DINNER + d] = S[n];
    sumdt[base * DINNER + d] = sdt;
}

__global__ __launch_bounds__(256)
void scan_pass2(const float* __restrict__ A_log,
                const float* __restrict__ sumdt,
                float* __restrict__ Sbuf)
{
    const int d = blockIdx.x * 256 + threadIdx.x;
    const int b = blockIdx.y;

    float Av[DSTATE];
    const bool pw = load_A(A_log, d, Av);
    const float Av0 = Av[0];

    float h[DSTATE];
    #pragma unroll
    for (int n = 0; n < DSTATE; ++n) h[n] = 0.f;

    for (int c = 0; c < NCH; ++c) {
        const size_t base = (size_t)b * NCH + c;
        const float sdt = sumdt[base * DINNER + d];
        if (pw) {
            const float e1 = __expf(sdt * Av0);
            float dA = 1.f;
            #pragma unroll
            for (int n = 0; n < DSTATE; ++n) {
                dA *= e1;
                const size_t idx = (base * DSTATE + n) * DINNER + d;
                const float tmp = Sbuf[idx];
                Sbuf[idx] = h[n];
                h[n] = fmaf(h[n], dA, tmp);
            }
        } else {
            #pragma unroll
            for (int n = 0; n < DSTATE; ++n) {
                const size_t idx = (base * DSTATE + n) * DINNER + d;
                const float tmp = Sbuf[idx];
                Sbuf[idx] = h[n];
                h[n] = fmaf(h[n], __expf(sdt * Av[n]), tmp);
            }
        }
    }
}

__global__ __launch_bounds__(256)
void scan_pass3(const f16* __restrict__ uh,
                const float* __restrict__ delta,
                const f16* __restrict__ zh,
                const float* __restrict__ proj,
                const float* __restrict__ A_log,
                const float* __restrict__ Dp,
                const float* __restrict__ Sbuf,
                f16* __restrict__ ygh)
{
    const int d = blockIdx.x * 256 + threadIdx.x;
    const int c = blockIdx.y;
    const int b = blockIdx.z;

    float Av[DSTATE];
    const bool pw = load_A(A_log, d, Av);
    const float Av0 = Av[0];

    float h[DSTATE];
    const size_t base = (size_t)b * NCH + c;
    #pragma unroll
    for (int n = 0; n < DSTATE; ++n)
        h[n] = Sbuf[(base * DSTATE + n) * DINNER + d];

    const float Dval = Dp[d];

    __shared__ float Bsh[CHUNK][DSTATE];
    __shared__ float Csh[CHUNK][DSTATE];
    const float* projb = proj + ((size_t)b * LSEQ + (size_t)c * CHUNK) * 96;
    #pragma unroll
    for (int i = 0; i < (CHUNK * 2 * DSTATE) / 256; ++i) {
        const int f = i * 256 + threadIdx.x;
        const int r = f >> 5, col = f & 31;
        const float v = projb[(size_t)r * 96 + 64 + col];
        if (col < DSTATE) Bsh[r][col] = v;
        else              Csh[r][col - DSTATE] = v;
    }
    __syncthreads();

    const size_t tok0 = (size_t)b * LSEQ + (size_t)c * CHUNK;
    for (int l = 0; l < CHUNK; ++l) {
        const size_t tok = tok0 + l;
        const float dt = delta[tok * DINNER + d];
        const float uu = (float)uh[tok * DINNER + d];
        const float zz = (float)zh[tok * DINNER + d];
        const float du = dt * uu;
        float y = 0.f;
        if (pw) {
            const float e1 = __expf(dt * Av0);
            float dA = 1.f;
            #pragma unroll
            for (int n = 0; n < DSTATE; ++n) {
                dA *= e1;
                h[n] = fmaf(h[n], dA, du * Bsh[l][n]);
                y = fmaf(h[n], Csh[l][n], y);
            }
        } else {
            #pragma unroll
            for (int n = 0; n < DSTATE; ++n) {
                h[n] = fmaf(h[n], __expf(dt * Av[n]), du * Bsh[l][n]);
                y = fmaf(h[n], Csh[l][n], y);
            }
        }
        const float yt = fmaf(uu, Dval, y);
        ygh[tok * DINNER + d] = (f16)(yt * silu_f(zz));
    }
}

// ---------------------------------------------------------------------------
extern "C" void kernel_launch(void* const* d_in, const int* in_sizes, int n_in,
                              void* d_out, int out_size, void* d_ws, size_t ws_size,
                              hipStream_t stream)
{
    const float* x     = (const float*)d_in[0];
    const float* W_in  = (const float*)d_in[1];
    const float* cw    = (const float*)d_in[2];
    const float* cb    = (const float*)d_in[3];
    const float* W_xp  = (const float*)d_in[4];
    const float* W_dt  = (const float*)d_in[5];
    const float* b_dt  = (const float*)d_in[6];
    const float* A_log = (const float*)d_in[7];
    const float* Dp    = (const float*)d_in[8];
    const float* W_out = (const float*)d_in[9];
    float* out = (float*)d_out;

    // ---- workspace layout, total 195.2 MB ----
    float* updelta = (float*)d_ws;                   // [MTOK][DINNER] f32: uph(f16) -> delta(f32)
    f16*   zh      = (f16*)(updelta + (size_t)MTOK * DINNER);   // [MTOK][DINNER] f16
    f16*   uh      = zh + (size_t)MTOK * DINNER;     // [MTOK][DINNER] f16 (xh alias at base)
    float* proj    = (float*)(uh + (size_t)MTOK * DINNER);      // [MTOK][96] f32
    f16*   projh   = (f16*)(proj + NPROJ);           // [MTOK][96] f16
    float* Sbuf    = (float*)(projh + NPROJ);        // [B][NCH][16][DINNER] f32
    float* sumdt   = Sbuf + (size_t)NBATCH * NCH * DSTATE * DINNER;
    f16*   WxpT    = (f16*)(sumdt + (size_t)NBATCH * NCH * DINNER);  // [96][DINNER]
    f16*   WdtT    = WxpT + (size_t)96 * DINNER;     // [DINNER][64]
    f16*   WoutT   = WdtT + (size_t)DINNER * DTRANK; // [DMODEL][DINNER]
    f16*   big     = WoutT + (size_t)DMODEL * DINNER;// 16.78M f16 alias region
    f16*   WinT    = big;                            // [NXZ][DMODEL] (phase 1)
    float* part3   = (float*)(big + (size_t)NXZ * DMODEL);  // [8][MTOK][96] (phase 2)
    f16*   ygh     = big;                            // [MTOK][DINNER] (phase 3)
    f16*   xh      = uh;                             // [MTOK][DMODEL] (pre-conv alias)
    f16*   uph     = (f16*)updelta;                  // [MTOK][DINNER] f16 (pre-conv, dead before delta)

    // 1) convert x, transpose-convert W_in
    cvt_f2h<<<(MTOK * DMODEL / 4 + 255) / 256, 256, 0, stream>>>(x, xh, MTOK * DMODEL / 4);
    tcvt<<<dim3(NXZ / 32, DMODEL / 32), 256, 0, stream>>>(W_in, WinT, DMODEL, NXZ);

    // 2) GEMM1a: u_pre = x @ W_in[:, :2048]   (f16 out)
    hgemm128<0, f16><<<dim3(64, 16), 256, 0, stream>>>(
        xh, DMODEL, WinT, DMODEL, uph, DINNER, DMODEL, nullptr);
    // 2b) GEMM1b: z = x @ W_in[:, 2048:]      (f16 out)
    hgemm128<0, f16><<<dim3(64, 16), 256, 0, stream>>>(
        xh, DMODEL, WinT + (size_t)DINNER * DMODEL, DMODEL, zh, DINNER, DMODEL, nullptr);

    // 3) conv + silu -> uh f16   (clobbers xh)
    conv_silu_kernel<<<(MTOK * 512) / 256, 256, 0, stream>>>(uph, cw, cb, uh);

    // 4) proj = u @ W_xproj  (split-K=8, N=96) + reduce
    tcvt<<<dim3(96 / 32, DINNER / 32), 256, 0, stream>>>(W_xp, WxpT, DINNER, 96);
    hgemm_n96<<<dim3(64, SPLITK), 256, 0, stream>>>(uh, WxpT, part3);
    reduce3<<<NPROJ / 256, 256, 0, stream>>>(part3, proj, projh);

    // 5) delta = softplus(proj[:, :64] @ W_dt + b_dt) -> updelta f32 (uph dead)
    tcvt<<<dim3(DINNER / 32, DTRANK / 32), 256, 0, stream>>>(W_dt, WdtT, DTRANK, DINNER);
    hgemm128<1, float><<<dim3(64, 16), 256, 0, stream>>>(
        projh, 96, WdtT, DTRANK, updelta, DINNER, DTRANK, b_dt);

    // 6) chunked scan + skip + gate -> ygh f16 (clobbers WinT/part3)
    scan_pass1<<<dim3(DINNER / 256, NCH, NBATCH), 256, 0, stream>>>(
        uh, updelta, proj, A_log, Sbuf, sumdt);
    scan_pass2<<<dim3(DINNER / 256, NBATCH), 256, 0, stream>>>(A_log, sumdt, Sbuf);
    scan_pass3<<<dim3(DINNER / 256, NCH, NBATCH), 256, 0, stream>>>(
        uh, updelta, zh, proj, A_log, Dp, Sbuf, ygh);

    // 7) out = yg @ W_out
    tcvt<<<dim3(DMODEL / 32, DINNER / 32), 256, 0, stream>>>(W_out, WoutT, DINNER, DMODEL);
    hgemm128<0, float><<<dim3(64, 8), 256, 0, stream>>>(
        ygh, DINNER, WoutT, DINNER, out, DMODEL, DINNER, nullptr);
}

// Round 8
// 337.340 us; speedup vs baseline: 9.4239x; 1.1327x over previous
//
#include <hip/hip_runtime.h>
#include <hip/hip_bf16.h>
#include <math.h>

// Problem constants
#define MTOK   8192   // B*L
#define LSEQ   2048
#define NBATCH 4
#define DMODEL 1024
#define DINNER 2048
#define DSTATE 16
#define DTRANK 64
#define NXZ    4096
#define CHUNK  64
#define NCH    32     // LSEQ / CHUNK
#define NPROJ  (MTOK * 96)
#define SPLITK 8

typedef _Float16 f16;
using f16x8 = __attribute__((ext_vector_type(8))) _Float16;
using f16x4 = __attribute__((ext_vector_type(4))) _Float16;
using f32x4 = __attribute__((ext_vector_type(4))) float;

__device__ __forceinline__ float silu_f(float x) { return x / (1.f + __expf(-x)); }

// async global->LDS, 16B per lane; lds dest = wave-uniform base + lane*16B
__device__ __forceinline__ void gload_lds16(const void* g, void* l) {
    __builtin_amdgcn_global_load_lds(
        (const __attribute__((address_space(1))) void*)g,
        (__attribute__((address_space(3))) void*)l, 16, 0, 0);
}

// ---------------------------------------------------------------------------
// f32 -> f16 elementwise (vec4)
// ---------------------------------------------------------------------------
__global__ __launch_bounds__(256)
void cvt_f2h(const float* __restrict__ in, f16* __restrict__ out, int n4)
{
    const int i = blockIdx.x * 256 + threadIdx.x;
    if (i >= n4) return;
    const float4 v = ((const float4*)in)[i];
    f16x4 o;
    o[0] = (f16)v.x; o[1] = (f16)v.y; o[2] = (f16)v.z; o[3] = (f16)v.w;
    ((f16x4*)out)[i] = o;
}

// ---------------------------------------------------------------------------
// Transpose + convert: in f32 [R][C] -> out f16 [C][R].  Grid (C/32, R/32).
// ---------------------------------------------------------------------------
__global__ __launch_bounds__(256)
void tcvt(const float* __restrict__ in, f16* __restrict__ out, int R, int C)
{
    __shared__ float t[32][33];
    const int c0 = blockIdx.x * 32, r0 = blockIdx.y * 32;
    const int tx = threadIdx.x & 31, ty = threadIdx.x >> 5;   // 32 x 8
    #pragma unroll
    for (int j = 0; j < 4; ++j)
        t[ty + 8 * j][tx] = in[(size_t)(r0 + ty + 8 * j) * C + c0 + tx];
    __syncthreads();
    #pragma unroll
    for (int j = 0; j < 4; ++j)
        out[(size_t)(c0 + ty + 8 * j) * R + r0 + tx] = (f16)t[tx][ty + 8 * j];
}

// ---------------------------------------------------------------------------
// FP16 MFMA GEMM with global_load_lds staging (m97 structure).
// C[M,N] = A[M,K] @ B[K,N]; A f16 [M][K] (lda), B TRANSPOSED f16 [N][K] (ldb).
// Tile 128x128, BK=32, 4 waves (2x2), each wave 64x64 (4x4 frags 16x16x32).
// Grid (M/128, N/128) exact.  EPI: 0 none, 1 fast-softplus(acc+bias[col]).
// ---------------------------------------------------------------------------
template<int EPI, typename OUT_T>
__global__ __launch_bounds__(256)
void hgemm128(const f16* __restrict__ A, int lda,
              const f16* __restrict__ Bt, int ldb,
              OUT_T* __restrict__ C, int ldc,
              int K, const float* __restrict__ bias)
{
    __shared__ __align__(16) f16 As[2][128 * 32];
    __shared__ __align__(16) f16 Bs[2][128 * 32];

    const int tid  = threadIdx.x;
    const int lane = tid & 63, wave = tid >> 6;
    const int wr = wave >> 1, wc = wave & 1;
    const int row0 = blockIdx.x * 128, col0 = blockIdx.y * 128;

    const int lrow = lane >> 2, lcol = (lane & 3) * 8;
    const f16* Agw = A  + (size_t)(row0 + wave * 32 + lrow) * lda + lcol;
    const f16* Bgw = Bt + (size_t)(col0 + wave * 32 + lrow) * ldb + lcol;
    const int ldsbase = (wave * 32) * 32;   // elems

    const int frow = lane & 15, fk = (lane >> 4) * 8;
    const int nt = K / 32;

    f32x4 acc[4][4] = {};

    #pragma unroll
    for (int r = 0; r < 2; ++r) {
        gload_lds16(Agw + (size_t)r * 16 * lda, &As[0][ldsbase + r * 16 * 32]);
        gload_lds16(Bgw + (size_t)r * 16 * ldb, &Bs[0][ldsbase + r * 16 * 32]);
    }

    int cur = 0;
    for (int kt = 0; kt < nt; ++kt) {
        __syncthreads();
        if (kt + 1 < nt) {
            const int k0 = (kt + 1) * 32;
            #pragma unroll
            for (int r = 0; r < 2; ++r) {
                gload_lds16(Agw + (size_t)r * 16 * lda + k0, &As[cur ^ 1][ldsbase + r * 16 * 32]);
                gload_lds16(Bgw + (size_t)r * 16 * ldb + k0, &Bs[cur ^ 1][ldsbase + r * 16 * 32]);
            }
        }
        f16x8 af[4], bf[4];
        #pragma unroll
        for (int m = 0; m < 4; ++m)
            af[m] = *(const f16x8*)&As[cur][(wr * 64 + m * 16 + frow) * 32 + fk];
        #pragma unroll
        for (int n = 0; n < 4; ++n)
            bf[n] = *(const f16x8*)&Bs[cur][(wc * 64 + n * 16 + frow) * 32 + fk];
        #pragma unroll
        for (int m = 0; m < 4; ++m)
            #pragma unroll
            for (int n = 0; n < 4; ++n)
                acc[m][n] = __builtin_amdgcn_mfma_f32_16x16x32_f16(af[m], bf[n], acc[m][n], 0, 0, 0);
        cur ^= 1;
    }

    const int rbase = row0 + wr * 64 + (lane >> 4) * 4;
    const int cbase = col0 + wc * 64 + (lane & 15);
    #pragma unroll
    for (int m = 0; m < 4; ++m) {
        #pragma unroll
        for (int n = 0; n < 4; ++n) {
            const int col = cbase + n * 16;
            #pragma unroll
            for (int r = 0; r < 4; ++r) {
                const int row = rbase + m * 16 + r;
                float tv = acc[m][n][r];
                if (EPI == 1) {
                    tv += bias[col];
                    tv = (tv > 20.f) ? tv : __logf(1.f + __expf(tv));
                }
                C[(size_t)row * ldc + col] = (OUT_T)tv;
            }
        }
    }
}

// ---------------------------------------------------------------------------
// Narrow-N GEMM for proj: part[sk] = uh[rows][kseg] @ WxpT^T, N=96, split-K=8.
// ---------------------------------------------------------------------------
__global__ __launch_bounds__(256)
void hgemm_n96(const f16* __restrict__ A,      // uh [MTOK][DINNER]
               const f16* __restrict__ Bt,     // WxpT [96][DINNER]
               float* __restrict__ part)       // [SPLITK][MTOK][96]
{
    __shared__ __align__(16) f16 As[128][40];
    __shared__ __align__(16) f16 Bs[96][40];

    const int tid = threadIdx.x, lane = tid & 63, wave = tid >> 6;
    const int row0 = blockIdx.x * 128;
    const int sk = blockIdx.y;
    const int kbase = sk * (DINNER / SPLITK);   // 256

    const int srow = tid >> 1, skoff = (tid & 1) * 16;
    const f16* Ag = A  + (size_t)(row0 + srow) * DINNER + kbase + skoff;
    const f16* Bg = Bt + (size_t)srow * DINNER + kbase + skoff;

    const int frow = lane & 15, fk = (lane >> 4) * 8;

    f32x4 acc[2][6] = {};

    for (int kk = 0; kk < DINNER / SPLITK; kk += 32) {
        const f16x8 a0 = *(const f16x8*)(Ag + kk);
        const f16x8 a1 = *(const f16x8*)(Ag + kk + 8);
        f16x8 b0 = {}, b1 = {};
        if (tid < 192) { b0 = *(const f16x8*)(Bg + kk); b1 = *(const f16x8*)(Bg + kk + 8); }
        __syncthreads();
        *(f16x8*)&As[srow][skoff]     = a0;
        *(f16x8*)&As[srow][skoff + 8] = a1;
        if (tid < 192) {
            *(f16x8*)&Bs[srow][skoff]     = b0;
            *(f16x8*)&Bs[srow][skoff + 8] = b1;
        }
        __syncthreads();

        f16x8 af[2], bf[6];
        #pragma unroll
        for (int m = 0; m < 2; ++m)
            af[m] = *(const f16x8*)&As[wave * 32 + m * 16 + frow][fk];
        #pragma unroll
        for (int n = 0; n < 6; ++n)
            bf[n] = *(const f16x8*)&Bs[n * 16 + frow][fk];
        #pragma unroll
        for (int m = 0; m < 2; ++m)
            #pragma unroll
            for (int n = 0; n < 6; ++n)
                acc[m][n] = __builtin_amdgcn_mfma_f32_16x16x32_f16(af[m], bf[n], acc[m][n], 0, 0, 0);
    }

    #pragma unroll
    for (int m = 0; m < 2; ++m)
        #pragma unroll
        for (int n = 0; n < 6; ++n) {
            const int col = n * 16 + (lane & 15);
            #pragma unroll
            for (int r = 0; r < 4; ++r) {
                const int row = row0 + wave * 32 + m * 16 + (lane >> 4) * 4 + r;
                part[((size_t)sk * MTOK + row) * 96 + col] = acc[m][n][r];
            }
        }
}

__global__ __launch_bounds__(256)
void reduce3(const float* __restrict__ part, float* __restrict__ proj,
             f16* __restrict__ projh)
{
    const int e = blockIdx.x * 256 + threadIdx.x;   // < NPROJ
    float s = 0.f;
    #pragma unroll
    for (int i = 0; i < SPLITK; ++i) s += part[(size_t)i * NPROJ + e];
    proj[e]  = s;
    projh[e] = (f16)s;
}

// ---------------------------------------------------------------------------
// Causal depthwise conv (D_CONV=4) + bias + SiLU, sliding-window.
// One thread: 8 tokens x 8 channels.  blockIdx.x = token octet, tid = d/8.
// Loads 11 rows of f16x8 (read amp 1.375x), writes 8.
// ---------------------------------------------------------------------------
__global__ __launch_bounds__(256)
void conv_silu_kernel(const f16* __restrict__ uph,
                      const float* __restrict__ cw, const float* __restrict__ cb,
                      f16* __restrict__ uh)
{
    const int mt  = blockIdx.x;          // 0 .. MTOK/8-1
    const int ml0 = mt * 8;
    const int l0  = ml0 & (LSEQ - 1);
    const int d   = threadIdx.x * 8;

    float w[8][4];
    #pragma unroll
    for (int c = 0; c < 8; ++c) {
        const float4 wv = *(const float4*)(cw + (size_t)(d + c) * 4);
        w[c][0] = wv.x; w[c][1] = wv.y; w[c][2] = wv.z; w[c][3] = wv.w;
    }
    float bias[8];
    {
        const float4 b0 = *(const float4*)(cb + d);
        const float4 b1 = *(const float4*)(cb + d + 4);
        bias[0] = b0.x; bias[1] = b0.y; bias[2] = b0.z; bias[3] = b0.w;
        bias[4] = b1.x; bias[5] = b1.y; bias[6] = b1.z; bias[7] = b1.w;
    }

    f16x8 r[11];
    if (l0 != 0) {
        #pragma unroll
        for (int i = 0; i < 11; ++i)
            r[i] = *(const f16x8*)(uph + (size_t)(ml0 - 3 + i) * DINNER + d);
    } else {
        r[0] = f16x8{}; r[1] = f16x8{}; r[2] = f16x8{};
        #pragma unroll
        for (int i = 3; i < 11; ++i)
            r[i] = *(const f16x8*)(uph + (size_t)(ml0 - 3 + i) * DINNER + d);
    }

    #pragma unroll
    for (int i = 0; i < 8; ++i) {
        f16x8 o;
        #pragma unroll
        for (int c = 0; c < 8; ++c) {
            float a = bias[c];
            #pragma unroll
            for (int j = 0; j < 4; ++j)
                a = fmaf((float)r[i + j][c], w[c][j], a);
            o[c] = (f16)silu_f(a);
        }
        *(f16x8*)(uh + (size_t)(ml0 + i) * DINNER + d) = o;
    }
}

// ---------------------------------------------------------------------------
// Chunked selective scan.  A-structure fast path: when A[d][n] = (n+1)*A[d][0]
// (true here: A = -[1..16]), exp(dt*A[n]) = e1^(n+1), e1=exp(dt*A0).
// Runtime-checked, generic fallback.
// ---------------------------------------------------------------------------
__device__ __forceinline__ bool load_A(const float* __restrict__ A_log, int d,
                                       float* Av)
{
    #pragma unroll
    for (int n = 0; n < DSTATE; ++n)
        Av[n] = -__expf(A_log[(size_t)d * DSTATE + n]);
    bool p = true;
    #pragma unroll
    for (int n = 1; n < DSTATE; ++n) {
        const float r = Av[n] / Av[0];
        if (fabsf(r - (float)(n + 1)) > 1e-3f) p = false;
    }
    return p;
}

__global__ __launch_bounds__(256)
void scan_pass1(const f16* __restrict__ uh,
                const f16* __restrict__ deltah,    // [MTOK][DINNER] f16
                const float* __restrict__ proj,    // [MTOK][96], 64..95 = B,C
                const float* __restrict__ A_log,
                float* __restrict__ Sbuf, float* __restrict__ sumdt)
{
    const int d = blockIdx.x * 256 + threadIdx.x;
    const int c = blockIdx.y;
    const int b = blockIdx.z;

    float Av[DSTATE];
    const bool pw = load_A(A_log, d, Av);
    const float Av0 = Av[0];

    __shared__ float Bsh[CHUNK][DSTATE];
    const float* projb = proj + ((size_t)b * LSEQ + (size_t)c * CHUNK) * 96;
    #pragma unroll
    for (int i = 0; i < (CHUNK * DSTATE) / 256; ++i) {
        const int f = i * 256 + threadIdx.x;
        Bsh[f >> 4][f & 15] = projb[(size_t)(f >> 4) * 96 + 64 + (f & 15)];
    }
    __syncthreads();

    float S[DSTATE];
    #pragma unroll
    for (int n = 0; n < DSTATE; ++n) S[n] = 0.f;
    float sdt = 0.f;

    const size_t tok0 = (size_t)b * LSEQ + (size_t)c * CHUNK;
    if (pw) {
        for (int l = 0; l < CHUNK; ++l) {
            const float dt = (float)deltah[(tok0 + l) * DINNER + d];
            const float uu = (float)uh[(tok0 + l) * DINNER + d];
            sdt += dt;
            const float du = dt * uu;
            const float e1 = __expf(dt * Av0);
            float dA = 1.f;
            #pragma unroll
            for (int n = 0; n < DSTATE; ++n) {
                dA *= e1;
                S[n] = fmaf(S[n], dA, du * Bsh[l][n]);
            }
        }
    } else {
        for (int l = 0; l < CHUNK; ++l) {
            const float dt = (float)deltah[(tok0 + l) * DINNER + d];
            const float uu = (float)uh[(tok0 + l) * DINNER + d];
            sdt += dt;
            const float du = dt * uu;
            #pragma unroll
            for (int n = 0; n < DSTATE; ++n)
                S[n] = fmaf(S[n], __expf(dt * Av[n]), du * Bsh[l][n]);
        }
    }

    const size_t base = (size_t)b * NCH + c;
    #pragma unroll
    for (int n = 0; n < DSTATE; ++n)
        Sbuf[(base * DSTATE + n) * DINNER + d] = S[n];
    sumdt[base * DINNER + d] = sdt;
}

__global__ __launch_bounds__(256)
void scan_pass2(const float* __restrict__ A_log,
                const float* __restrict__ sumdt,
                float* __restrict__ Sbuf)
{
    const int d = blockIdx.x * 256 + threadIdx.x;
    const int b = blockIdx.y;

    float Av[DSTATE];
    const bool pw = load_A(A_log, d, Av);
    const float Av0 = Av[0];

    float h[DSTATE];
    #pragma unroll
    for (int n = 0; n < DSTATE; ++n) h[n] = 0.f;

    for (int c = 0; c < NCH; ++c) {
        const size_t base = (size_t)b * NCH + c;
        const float sdt = sumdt[base * DINNER + d];
        if (pw) {
            const float e1 = __expf(sdt * Av0);
            float dA = 1.f;
            #pragma unroll
            for (int n = 0; n < DSTATE; ++n) {
                dA *= e1;
                const size_t idx = (base * DSTATE + n) * DINNER + d;
                const float tmp = Sbuf[idx];
                Sbuf[idx] = h[n];
                h[n] = fmaf(h[n], dA, tmp);
            }
        } else {
            #pragma unroll
            for (int n = 0; n < DSTATE; ++n) {
                const size_t idx = (base * DSTATE + n) * DINNER + d;
                const float tmp = Sbuf[idx];
                Sbuf[idx] = h[n];
                h[n] = fmaf(h[n], __expf(sdt * Av[n]), tmp);
            }
        }
    }
}

__global__ __launch_bounds__(256)
void scan_pass3(const f16* __restrict__ uh,
                const f16* __restrict__ deltah,
                const f16* __restrict__ zh,
                const float* __restrict__ proj,
                const float* __restrict__ A_log,
                const float* __restrict__ Dp,
                const float* __restrict__ Sbuf,
                f16* __restrict__ ygh)
{
    const int d = blockIdx.x * 256 + threadIdx.x;
    const int c = blockIdx.y;
    const int b = blockIdx.z;

    float Av[DSTATE];
    const bool pw = load_A(A_log, d, Av);
    const float Av0 = Av[0];

    float h[DSTATE];
    const size_t base = (size_t)b * NCH + c;
    #pragma unroll
    for (int n = 0; n < DSTATE; ++n)
        h[n] = Sbuf[(base * DSTATE + n) * DINNER + d];

    const float Dval = Dp[d];

    __shared__ float Bsh[CHUNK][DSTATE];
    __shared__ float Csh[CHUNK][DSTATE];
    const float* projb = proj + ((size_t)b * LSEQ + (size_t)c * CHUNK) * 96;
    #pragma unroll
    for (int i = 0; i < (CHUNK * 2 * DSTATE) / 256; ++i) {
        const int f = i * 256 + threadIdx.x;
        const int r = f >> 5, col = f & 31;
        const float v = projb[(size_t)r * 96 + 64 + col];
        if (col < DSTATE) Bsh[r][col] = v;
        else              Csh[r][col - DSTATE] = v;
    }
    __syncthreads();

    const size_t tok0 = (size_t)b * LSEQ + (size_t)c * CHUNK;
    for (int l = 0; l < CHUNK; ++l) {
        const size_t tok = tok0 + l;
        const float dt = (float)deltah[tok * DINNER + d];
        const float uu = (float)uh[tok * DINNER + d];
        const float zz = (float)zh[tok * DINNER + d];
        const float du = dt * uu;
        float y = 0.f;
        if (pw) {
            const float e1 = __expf(dt * Av0);
            float dA = 1.f;
            #pragma unroll
            for (int n = 0; n < DSTATE; ++n) {
                dA *= e1;
                h[n] = fmaf(h[n], dA, du * Bsh[l][n]);
                y = fmaf(h[n], Csh[l][n], y);
            }
        } else {
            #pragma unroll
            for (int n = 0; n < DSTATE; ++n) {
                h[n] = fmaf(h[n], __expf(dt * Av[n]), du * Bsh[l][n]);
                y = fmaf(h[n], Csh[l][n], y);
            }
        }
        const float yt = fmaf(uu, Dval, y);
        ygh[tok * DINNER + d] = (f16)(yt * silu_f(zz));
    }
}

// ---------------------------------------------------------------------------
extern "C" void kernel_launch(void* const* d_in, const int* in_sizes, int n_in,
                              void* d_out, int out_size, void* d_ws, size_t ws_size,
                              hipStream_t stream)
{
    const float* x     = (const float*)d_in[0];
    const float* W_in  = (const float*)d_in[1];
    const float* cw    = (const float*)d_in[2];
    const float* cb    = (const float*)d_in[3];
    const float* W_xp  = (const float*)d_in[4];
    const float* W_dt  = (const float*)d_in[5];
    const float* b_dt  = (const float*)d_in[6];
    const float* A_log = (const float*)d_in[7];
    const float* Dp    = (const float*)d_in[8];
    const float* W_out = (const float*)d_in[9];
    float* out = (float*)d_out;

    // ---- workspace layout, total 195.2 MB ----
    float* updelta = (float*)d_ws;                   // [MTOK][DINNER] f32 region: uph(f16) -> deltah(f16)
    f16*   zh      = (f16*)(updelta + (size_t)MTOK * DINNER);   // [MTOK][DINNER] f16
    f16*   uh      = zh + (size_t)MTOK * DINNER;     // [MTOK][DINNER] f16 (xh alias at base)
    float* proj    = (float*)(uh + (size_t)MTOK * DINNER);      // [MTOK][96] f32
    f16*   projh   = (f16*)(proj + NPROJ);           // [MTOK][96] f16
    float* Sbuf    = (float*)(projh + NPROJ);        // [B][NCH][16][DINNER] f32
    float* sumdt   = Sbuf + (size_t)NBATCH * NCH * DSTATE * DINNER;
    f16*   WxpT    = (f16*)(sumdt + (size_t)NBATCH * NCH * DINNER);  // [96][DINNER]
    f16*   WdtT    = WxpT + (size_t)96 * DINNER;     // [DINNER][64]
    f16*   WoutT   = WdtT + (size_t)DINNER * DTRANK; // [DMODEL][DINNER]
    f16*   big     = WoutT + (size_t)DMODEL * DINNER;// 16.78M f16 alias region
    f16*   WinT    = big;                            // [NXZ][DMODEL] (phase 1)
    float* part3   = (float*)(big + (size_t)NXZ * DMODEL);  // [8][MTOK][96] (phase 2)
    f16*   ygh     = big;                            // [MTOK][DINNER] (phase 3)
    f16*   xh      = uh;                             // [MTOK][DMODEL] (pre-conv alias)
    f16*   uph     = (f16*)updelta;                  // [MTOK][DINNER] f16 (dead before delta)
    f16*   deltah  = (f16*)updelta;                  // [MTOK][DINNER] f16 (over uph)

    // 1) convert x, transpose-convert W_in
    cvt_f2h<<<(MTOK * DMODEL / 4 + 255) / 256, 256, 0, stream>>>(x, xh, MTOK * DMODEL / 4);
    tcvt<<<dim3(NXZ / 32, DMODEL / 32), 256, 0, stream>>>(W_in, WinT, DMODEL, NXZ);

    // 2) GEMM1a: u_pre = x @ W_in[:, :2048]   (f16 out)
    hgemm128<0, f16><<<dim3(64, 16), 256, 0, stream>>>(
        xh, DMODEL, WinT, DMODEL, uph, DINNER, DMODEL, nullptr);
    // 2b) GEMM1b: z = x @ W_in[:, 2048:]      (f16 out)
    hgemm128<0, f16><<<dim3(64, 16), 256, 0, stream>>>(
        xh, DMODEL, WinT + (size_t)DINNER * DMODEL, DMODEL, zh, DINNER, DMODEL, nullptr);

    // 3) conv + silu -> uh f16   (clobbers xh)
    conv_silu_kernel<<<MTOK / 8, 256, 0, stream>>>(uph, cw, cb, uh);

    // 4) proj = u @ W_xproj  (split-K=8, N=96) + reduce
    tcvt<<<dim3(96 / 32, DINNER / 32), 256, 0, stream>>>(W_xp, WxpT, DINNER, 96);
    hgemm_n96<<<dim3(64, SPLITK), 256, 0, stream>>>(uh, WxpT, part3);
    reduce3<<<NPROJ / 256, 256, 0, stream>>>(part3, proj, projh);

    // 5) deltah = softplus(proj[:, :64] @ W_dt + b_dt) f16 (uph dead)
    tcvt<<<dim3(DINNER / 32, DTRANK / 32), 256, 0, stream>>>(W_dt, WdtT, DTRANK, DINNER);
    hgemm128<1, f16><<<dim3(64, 16), 256, 0, stream>>>(
        projh, 96, WdtT, DTRANK, deltah, DINNER, DTRANK, b_dt);

    // 6) chunked scan + skip + gate -> ygh f16 (clobbers WinT/part3)
    scan_pass1<<<dim3(DINNER / 256, NCH, NBATCH), 256, 0, stream>>>(
        uh, deltah, proj, A_log, Sbuf, sumdt);
    scan_pass2<<<dim3(DINNER / 256, NBATCH), 256, 0, stream>>>(A_log, sumdt, Sbuf);
    scan_pass3<<<dim3(DINNER / 256, NCH, NBATCH), 256, 0, stream>>>(
        uh, deltah, zh, proj, A_log, Dp, Sbuf, ygh);

    // 7) out = yg @ W_out
    tcvt<<<dim3(DMODEL / 32, DINNER / 32), 256, 0, stream>>>(W_out, WoutT, DINNER, DMODEL);
    hgemm128<0, float><<<dim3(64, 8), 256, 0, stream>>>(
        ygh, DINNER, WoutT, DINNER, out, DMODEL, DINNER, nullptr);
}

// Round 9
// 325.669 us; speedup vs baseline: 9.7617x; 1.0358x over previous
//
#include <hip/hip_runtime.h>
#include <hip/hip_bf16.h>
#include <math.h>

// Problem constants
#define MTOK   8192   // B*L
#define LSEQ   2048
#define NBATCH 4
#define DMODEL 1024
#define DINNER 2048
#define DSTATE 16
#define DTRANK 64
#define NXZ    4096
#define CHUNK  64
#define NCH    32     // LSEQ / CHUNK
#define NPROJ  (MTOK * 96)
#define SPLITK 8

typedef _Float16 f16;
using f16x8 = __attribute__((ext_vector_type(8))) _Float16;
using f16x4 = __attribute__((ext_vector_type(4))) _Float16;
using f32x4 = __attribute__((ext_vector_type(4))) float;

__device__ __forceinline__ float silu_f(float x) { return x / (1.f + __expf(-x)); }

// async global->LDS, 16B per lane; lds dest = wave-uniform base + lane*16B
__device__ __forceinline__ void gload_lds16(const void* g, void* l) {
    __builtin_amdgcn_global_load_lds(
        (const __attribute__((address_space(1))) void*)g,
        (__attribute__((address_space(3))) void*)l, 16, 0, 0);
}

// ---------------------------------------------------------------------------
// f32 -> f16 elementwise (vec4)
// ---------------------------------------------------------------------------
__global__ __launch_bounds__(256)
void cvt_f2h(const float* __restrict__ in, f16* __restrict__ out, int n4)
{
    const int i = blockIdx.x * 256 + threadIdx.x;
    if (i >= n4) return;
    const float4 v = ((const float4*)in)[i];
    f16x4 o;
    o[0] = (f16)v.x; o[1] = (f16)v.y; o[2] = (f16)v.z; o[3] = (f16)v.w;
    ((f16x4*)out)[i] = o;
}

// ---------------------------------------------------------------------------
// Transpose + convert: in f32 [R][C] -> out f16 [C][R].  Grid (C/32, R/32).
// ---------------------------------------------------------------------------
__global__ __launch_bounds__(256)
void tcvt(const float* __restrict__ in, f16* __restrict__ out, int R, int C)
{
    __shared__ float t[32][33];
    const int c0 = blockIdx.x * 32, r0 = blockIdx.y * 32;
    const int tx = threadIdx.x & 31, ty = threadIdx.x >> 5;   // 32 x 8
    #pragma unroll
    for (int j = 0; j < 4; ++j)
        t[ty + 8 * j][tx] = in[(size_t)(r0 + ty + 8 * j) * C + c0 + tx];
    __syncthreads();
    #pragma unroll
    for (int j = 0; j < 4; ++j)
        out[(size_t)(c0 + ty + 8 * j) * R + r0 + tx] = (f16)t[tx][ty + 8 * j];
}

// ---------------------------------------------------------------------------
// FP16 MFMA GEMM with global_load_lds staging (m97 structure).
// C[M,N] = A[M,K] @ B[K,N]; A f16 [M][K] (lda), B TRANSPOSED f16 [N][K] (ldb).
// Tile 128x128, BK=32, 4 waves (2x2), each wave 64x64 (4x4 frags 16x16x32).
// Grid (M/128, N/128) exact.  EPI: 0 none, 1 fast-softplus(acc+bias[col]).
// If C2 != null: blocks with col0 >= splitcol write to C2 at (col - splitcol)
// (splitcol must be a multiple of 128; block-uniform).
// ---------------------------------------------------------------------------
template<int EPI, typename OUT_T>
__global__ __launch_bounds__(256)
void hgemm128(const f16* __restrict__ A, int lda,
              const f16* __restrict__ Bt, int ldb,
              OUT_T* __restrict__ C, int ldc,
              int K, const float* __restrict__ bias,
              OUT_T* __restrict__ C2, int splitcol)
{
    __shared__ __align__(16) f16 As[2][128 * 32];
    __shared__ __align__(16) f16 Bs[2][128 * 32];

    const int tid  = threadIdx.x;
    const int lane = tid & 63, wave = tid >> 6;
    const int wr = wave >> 1, wc = wave & 1;
    const int row0 = blockIdx.x * 128;
    int col0 = blockIdx.y * 128;

    const int lrow = lane >> 2, lcol = (lane & 3) * 8;
    const f16* Agw = A  + (size_t)(row0 + wave * 32 + lrow) * lda + lcol;
    const f16* Bgw = Bt + (size_t)(col0 + wave * 32 + lrow) * ldb + lcol;
    const int ldsbase = (wave * 32) * 32;   // elems

    const int frow = lane & 15, fk = (lane >> 4) * 8;
    const int nt = K / 32;

    f32x4 acc[4][4] = {};

    #pragma unroll
    for (int r = 0; r < 2; ++r) {
        gload_lds16(Agw + (size_t)r * 16 * lda, &As[0][ldsbase + r * 16 * 32]);
        gload_lds16(Bgw + (size_t)r * 16 * ldb, &Bs[0][ldsbase + r * 16 * 32]);
    }

    int cur = 0;
    for (int kt = 0; kt < nt; ++kt) {
        __syncthreads();
        if (kt + 1 < nt) {
            const int k0 = (kt + 1) * 32;
            #pragma unroll
            for (int r = 0; r < 2; ++r) {
                gload_lds16(Agw + (size_t)r * 16 * lda + k0, &As[cur ^ 1][ldsbase + r * 16 * 32]);
                gload_lds16(Bgw + (size_t)r * 16 * ldb + k0, &Bs[cur ^ 1][ldsbase + r * 16 * 32]);
            }
        }
        f16x8 af[4], bf[4];
        #pragma unroll
        for (int m = 0; m < 4; ++m)
            af[m] = *(const f16x8*)&As[cur][(wr * 64 + m * 16 + frow) * 32 + fk];
        #pragma unroll
        for (int n = 0; n < 4; ++n)
            bf[n] = *(const f16x8*)&Bs[cur][(wc * 64 + n * 16 + frow) * 32 + fk];
        #pragma unroll
        for (int m = 0; m < 4; ++m)
            #pragma unroll
            for (int n = 0; n < 4; ++n)
                acc[m][n] = __builtin_amdgcn_mfma_f32_16x16x32_f16(af[m], bf[n], acc[m][n], 0, 0, 0);
        cur ^= 1;
    }

    OUT_T* Cw = C;
    if (C2 != nullptr && col0 >= splitcol) { Cw = C2; col0 -= splitcol; }

    const int rbase = row0 + wr * 64 + (lane >> 4) * 4;
    const int cbase = col0 + wc * 64 + (lane & 15);
    #pragma unroll
    for (int m = 0; m < 4; ++m) {
        #pragma unroll
        for (int n = 0; n < 4; ++n) {
            const int col = cbase + n * 16;
            #pragma unroll
            for (int r = 0; r < 4; ++r) {
                const int row = rbase + m * 16 + r;
                float tv = acc[m][n][r];
                if (EPI == 1) {
                    tv += bias[col];
                    tv = (tv > 20.f) ? tv : __logf(1.f + __expf(tv));
                }
                Cw[(size_t)row * ldc + col] = (OUT_T)tv;
            }
        }
    }
}

// ---------------------------------------------------------------------------
// Narrow-N GEMM for proj: part[sk] = uh[rows][kseg] @ WxpT^T, N=96, split-K=8.
// ---------------------------------------------------------------------------
__global__ __launch_bounds__(256)
void hgemm_n96(const f16* __restrict__ A,      // uh [MTOK][DINNER]
               const f16* __restrict__ Bt,     // WxpT [96][DINNER]
               float* __restrict__ part)       // [SPLITK][MTOK][96]
{
    __shared__ __align__(16) f16 As[128][40];
    __shared__ __align__(16) f16 Bs[96][40];

    const int tid = threadIdx.x, lane = tid & 63, wave = tid >> 6;
    const int row0 = blockIdx.x * 128;
    const int sk = blockIdx.y;
    const int kbase = sk * (DINNER / SPLITK);   // 256

    const int srow = tid >> 1, skoff = (tid & 1) * 16;
    const f16* Ag = A  + (size_t)(row0 + srow) * DINNER + kbase + skoff;
    const f16* Bg = Bt + (size_t)srow * DINNER + kbase + skoff;

    const int frow = lane & 15, fk = (lane >> 4) * 8;

    f32x4 acc[2][6] = {};

    for (int kk = 0; kk < DINNER / SPLITK; kk += 32) {
        const f16x8 a0 = *(const f16x8*)(Ag + kk);
        const f16x8 a1 = *(const f16x8*)(Ag + kk + 8);
        f16x8 b0 = {}, b1 = {};
        if (tid < 192) { b0 = *(const f16x8*)(Bg + kk); b1 = *(const f16x8*)(Bg + kk + 8); }
        __syncthreads();
        *(f16x8*)&As[srow][skoff]     = a0;
        *(f16x8*)&As[srow][skoff + 8] = a1;
        if (tid < 192) {
            *(f16x8*)&Bs[srow][skoff]     = b0;
            *(f16x8*)&Bs[srow][skoff + 8] = b1;
        }
        __syncthreads();

        f16x8 af[2], bf[6];
        #pragma unroll
        for (int m = 0; m < 2; ++m)
            af[m] = *(const f16x8*)&As[wave * 32 + m * 16 + frow][fk];
        #pragma unroll
        for (int n = 0; n < 6; ++n)
            bf[n] = *(const f16x8*)&Bs[n * 16 + frow][fk];
        #pragma unroll
        for (int m = 0; m < 2; ++m)
            #pragma unroll
            for (int n = 0; n < 6; ++n)
                acc[m][n] = __builtin_amdgcn_mfma_f32_16x16x32_f16(af[m], bf[n], acc[m][n], 0, 0, 0);
    }

    #pragma unroll
    for (int m = 0; m < 2; ++m)
        #pragma unroll
        for (int n = 0; n < 6; ++n) {
            const int col = n * 16 + (lane & 15);
            #pragma unroll
            for (int r = 0; r < 4; ++r) {
                const int row = row0 + wave * 32 + m * 16 + (lane >> 4) * 4 + r;
                part[((size_t)sk * MTOK + row) * 96 + col] = acc[m][n][r];
            }
        }
}

__global__ __launch_bounds__(256)
void reduce3(const float* __restrict__ part, float* __restrict__ proj,
             f16* __restrict__ projh)
{
    const int e = blockIdx.x * 256 + threadIdx.x;   // < NPROJ
    float s = 0.f;
    #pragma unroll
    for (int i = 0; i < SPLITK; ++i) s += part[(size_t)i * NPROJ + e];
    proj[e]  = s;
    projh[e] = (f16)s;
}

// ---------------------------------------------------------------------------
// Causal depthwise conv (D_CONV=4) + bias + SiLU, sliding-window.
// One thread: 8 tokens x 8 channels.
// ---------------------------------------------------------------------------
__global__ __launch_bounds__(256)
void conv_silu_kernel(const f16* __restrict__ uph,
                      const float* __restrict__ cw, const float* __restrict__ cb,
                      f16* __restrict__ uh)
{
    const int mt  = blockIdx.x;          // 0 .. MTOK/8-1
    const int ml0 = mt * 8;
    const int l0  = ml0 & (LSEQ - 1);
    const int d   = threadIdx.x * 8;

    float w[8][4];
    #pragma unroll
    for (int c = 0; c < 8; ++c) {
        const float4 wv = *(const float4*)(cw + (size_t)(d + c) * 4);
        w[c][0] = wv.x; w[c][1] = wv.y; w[c][2] = wv.z; w[c][3] = wv.w;
    }
    float bias[8];
    {
        const float4 b0 = *(const float4*)(cb + d);
        const float4 b1 = *(const float4*)(cb + d + 4);
        bias[0] = b0.x; bias[1] = b0.y; bias[2] = b0.z; bias[3] = b0.w;
        bias[4] = b1.x; bias[5] = b1.y; bias[6] = b1.z; bias[7] = b1.w;
    }

    f16x8 r[11];
    if (l0 != 0) {
        #pragma unroll
        for (int i = 0; i < 11; ++i)
            r[i] = *(const f16x8*)(uph + (size_t)(ml0 - 3 + i) * DINNER + d);
    } else {
        r[0] = f16x8{}; r[1] = f16x8{}; r[2] = f16x8{};
        #pragma unroll
        for (int i = 3; i < 11; ++i)
            r[i] = *(const f16x8*)(uph + (size_t)(ml0 - 3 + i) * DINNER + d);
    }

    #pragma unroll
    for (int i = 0; i < 8; ++i) {
        f16x8 o;
        #pragma unroll
        for (int c = 0; c < 8; ++c) {
            float a = bias[c];
            #pragma unroll
            for (int j = 0; j < 4; ++j)
                a = fmaf((float)r[i + j][c], w[c][j], a);
            o[c] = (f16)silu_f(a);
        }
        *(f16x8*)(uh + (size_t)(ml0 + i) * DINNER + d) = o;
    }
}

// ---------------------------------------------------------------------------
// Chunked selective scan.  A-structure fast path: when A[d][n] = (n+1)*A[d][0]
// (true here: A = -[1..16]), exp(dt*A[n]) = e1^(n+1), e1=exp(dt*A0).
// Power ladder breaks the 16-mul serial chain to depth ~4:
//   p1..p4 = e1^{1..4}; group multiplier m *= p4; dA(n=4g+j) = m_prev * p_j.
// Runtime-checked, generic fallback.
// ---------------------------------------------------------------------------
__device__ __forceinline__ bool load_A(const float* __restrict__ A_log, int d,
                                       float* Av)
{
    #pragma unroll
    for (int n = 0; n < DSTATE; ++n)
        Av[n] = -__expf(A_log[(size_t)d * DSTATE + n]);
    bool p = true;
    #pragma unroll
    for (int n = 1; n < DSTATE; ++n) {
        const float r = Av[n] / Av[0];
        if (fabsf(r - (float)(n + 1)) > 1e-3f) p = false;
    }
    return p;
}

__global__ __launch_bounds__(256)
void scan_pass1(const f16* __restrict__ uh,
                const f16* __restrict__ deltah,    // [MTOK][DINNER] f16
                const float* __restrict__ proj,    // [MTOK][96], 64..95 = B,C
                const float* __restrict__ A_log,
                float* __restrict__ Sbuf, float* __restrict__ sumdt)
{
    const int d = blockIdx.x * 256 + threadIdx.x;
    const int c = blockIdx.y;
    const int b = blockIdx.z;

    float Av[DSTATE];
    const bool pw = load_A(A_log, d, Av);
    const float Av0 = Av[0];

    __shared__ __align__(16) float Bsh[CHUNK][DSTATE];
    const float* projb = proj + ((size_t)b * LSEQ + (size_t)c * CHUNK) * 96;
    #pragma unroll
    for (int i = 0; i < (CHUNK * DSTATE) / 256; ++i) {
        const int f = i * 256 + threadIdx.x;
        Bsh[f >> 4][f & 15] = projb[(size_t)(f >> 4) * 96 + 64 + (f & 15)];
    }
    __syncthreads();

    float S[DSTATE];
    #pragma unroll
    for (int n = 0; n < DSTATE; ++n) S[n] = 0.f;
    float sdt = 0.f;

    const size_t tok0 = (size_t)b * LSEQ + (size_t)c * CHUNK;
    if (pw) {
        for (int l = 0; l < CHUNK; ++l) {
            const float dt = (float)deltah[(tok0 + l) * DINNER + d];
            const float uu = (float)uh[(tok0 + l) * DINNER + d];
            sdt += dt;
            const float du = dt * uu;
            const float p1 = __expf(dt * Av0);
            const float p2 = p1 * p1;
            const float p3 = p2 * p1;
            const float p4 = p2 * p2;
            float m = 1.f;
            #pragma unroll
            for (int g = 0; g < 4; ++g) {
                const f32x4 bb = *(const f32x4*)&Bsh[l][g * 4];
                S[g*4+0] = fmaf(S[g*4+0], m * p1, du * bb[0]);
                S[g*4+1] = fmaf(S[g*4+1], m * p2, du * bb[1]);
                S[g*4+2] = fmaf(S[g*4+2], m * p3, du * bb[2]);
                S[g*4+3] = fmaf(S[g*4+3], m * p4, du * bb[3]);
                m *= p4;
            }
        }
    } else {
        for (int l = 0; l < CHUNK; ++l) {
            const float dt = (float)deltah[(tok0 + l) * DINNER + d];
            const float uu = (float)uh[(tok0 + l) * DINNER + d];
            sdt += dt;
            const float du = dt * uu;
            #pragma unroll
            for (int n = 0; n < DSTATE; ++n)
                S[n] = fmaf(S[n], __expf(dt * Av[n]), du * Bsh[l][n]);
        }
    }

    const size_t base = (size_t)b * NCH + c;
    #pragma unroll
    for (int n = 0; n < DSTATE; ++n)
        Sbuf[(base * DSTATE + n) * DINNER + d] = S[n];
    sumdt[base * DINNER + d] = sdt;
}

__global__ __launch_bounds__(256)
void scan_pass2(const float* __restrict__ A_log,
                const float* __restrict__ sumdt,
                float* __restrict__ Sbuf)
{
    const int d = blockIdx.x * 256 + threadIdx.x;
    const int b = blockIdx.y;

    float Av[DSTATE];
    const bool pw = load_A(A_log, d, Av);
    const float Av0 = Av[0];

    float h[DSTATE];
    #pragma unroll
    for (int n = 0; n < DSTATE; ++n) h[n] = 0.f;

    for (int c = 0; c < NCH; ++c) {
        const size_t base = (size_t)b * NCH + c;
        const float sdt = sumdt[base * DINNER + d];
        if (pw) {
            const float p1 = __expf(sdt * Av0);
            const float p2 = p1 * p1;
            const float p3 = p2 * p1;
            const float p4 = p2 * p2;
            float m = 1.f;
            #pragma unroll
            for (int g = 0; g < 4; ++g) {
                const float pj[4] = {p1, p2, p3, p4};
                #pragma unroll
                for (int j = 0; j < 4; ++j) {
                    const int n = g * 4 + j;
                    const size_t idx = (base * DSTATE + n) * DINNER + d;
                    const float tmp = Sbuf[idx];
                    Sbuf[idx] = h[n];
                    h[n] = fmaf(h[n], m * pj[j], tmp);
                }
                m *= p4;
            }
        } else {
            #pragma unroll
            for (int n = 0; n < DSTATE; ++n) {
                const size_t idx = (base * DSTATE + n) * DINNER + d;
                const float tmp = Sbuf[idx];
                Sbuf[idx] = h[n];
                h[n] = fmaf(h[n], __expf(sdt * Av[n]), tmp);
            }
        }
    }
}

__global__ __launch_bounds__(256)
void scan_pass3(const f16* __restrict__ uh,
                const f16* __restrict__ deltah,
                const f16* __restrict__ zh,
                const float* __restrict__ proj,
                const float* __restrict__ A_log,
                const float* __restrict__ Dp,
                const float* __restrict__ Sbuf,
                f16* __restrict__ ygh)
{
    const int d = blockIdx.x * 256 + threadIdx.x;
    const int c = blockIdx.y;
    const int b = blockIdx.z;

    float Av[DSTATE];
    const bool pw = load_A(A_log, d, Av);
    const float Av0 = Av[0];

    float h[DSTATE];
    const size_t base = (size_t)b * NCH + c;
    #pragma unroll
    for (int n = 0; n < DSTATE; ++n)
        h[n] = Sbuf[(base * DSTATE + n) * DINNER + d];

    const float Dval = Dp[d];

    __shared__ __align__(16) float Bsh[CHUNK][DSTATE];
    __shared__ __align__(16) float Csh[CHUNK][DSTATE];
    const float* projb = proj + ((size_t)b * LSEQ + (size_t)c * CHUNK) * 96;
    #pragma unroll
    for (int i = 0; i < (CHUNK * 2 * DSTATE) / 256; ++i) {
        const int f = i * 256 + threadIdx.x;
        const int r = f >> 5, col = f & 31;
        const float v = projb[(size_t)r * 96 + 64 + col];
        if (col < DSTATE) Bsh[r][col] = v;
        else              Csh[r][col - DSTATE] = v;
    }
    __syncthreads();

    const size_t tok0 = (size_t)b * LSEQ + (size_t)c * CHUNK;
    for (int l = 0; l < CHUNK; ++l) {
        const size_t tok = tok0 + l;
        const float dt = (float)deltah[tok * DINNER + d];
        const float uu = (float)uh[tok * DINNER + d];
        const float zz = (float)zh[tok * DINNER + d];
        const float du = dt * uu;
        float y = 0.f;
        if (pw) {
            const float p1 = __expf(dt * Av0);
            const float p2 = p1 * p1;
            const float p3 = p2 * p1;
            const float p4 = p2 * p2;
            float m = 1.f;
            #pragma unroll
            for (int g = 0; g < 4; ++g) {
                const f32x4 bb = *(const f32x4*)&Bsh[l][g * 4];
                const f32x4 cc = *(const f32x4*)&Csh[l][g * 4];
                h[g*4+0] = fmaf(h[g*4+0], m * p1, du * bb[0]);
                h[g*4+1] = fmaf(h[g*4+1], m * p2, du * bb[1]);
                h[g*4+2] = fmaf(h[g*4+2], m * p3, du * bb[2]);
                h[g*4+3] = fmaf(h[g*4+3], m * p4, du * bb[3]);
                y = fmaf(h[g*4+0], cc[0], y);
                y = fmaf(h[g*4+1], cc[1], y);
                y = fmaf(h[g*4+2], cc[2], y);
                y = fmaf(h[g*4+3], cc[3], y);
                m *= p4;
            }
        } else {
            #pragma unroll
            for (int n = 0; n < DSTATE; ++n) {
                h[n] = fmaf(h[n], __expf(dt * Av[n]), du * Bsh[l][n]);
                y = fmaf(h[n], Csh[l][n], y);
            }
        }
        const float yt = fmaf(uu, Dval, y);
        ygh[tok * DINNER + d] = (f16)(yt * silu_f(zz));
    }
}

// ---------------------------------------------------------------------------
extern "C" void kernel_launch(void* const* d_in, const int* in_sizes, int n_in,
                              void* d_out, int out_size, void* d_ws, size_t ws_size,
                              hipStream_t stream)
{
    const float* x     = (const float*)d_in[0];
    const float* W_in  = (const float*)d_in[1];
    const float* cw    = (const float*)d_in[2];
    const float* cb    = (const float*)d_in[3];
    const float* W_xp  = (const float*)d_in[4];
    const float* W_dt  = (const float*)d_in[5];
    const float* b_dt  = (const float*)d_in[6];
    const float* A_log = (const float*)d_in[7];
    const float* Dp    = (const float*)d_in[8];
    const float* W_out = (const float*)d_in[9];
    float* out = (float*)d_out;

    // ---- workspace layout, total 195.2 MB ----
    float* updelta = (float*)d_ws;                   // [MTOK][DINNER] f32 region: uph(f16) -> deltah(f16)
    f16*   zh      = (f16*)(updelta + (size_t)MTOK * DINNER);   // [MTOK][DINNER] f16
    f16*   uh      = zh + (size_t)MTOK * DINNER;     // [MTOK][DINNER] f16 (xh alias at base)
    float* proj    = (float*)(uh + (size_t)MTOK * DINNER);      // [MTOK][96] f32
    f16*   projh   = (f16*)(proj + NPROJ);           // [MTOK][96] f16
    float* Sbuf    = (float*)(projh + NPROJ);        // [B][NCH][16][DINNER] f32
    float* sumdt   = Sbuf + (size_t)NBATCH * NCH * DSTATE * DINNER;
    f16*   WxpT    = (f16*)(sumdt + (size_t)NBATCH * NCH * DINNER);  // [96][DINNER]
    f16*   WdtT    = WxpT + (size_t)96 * DINNER;     // [DINNER][64]
    f16*   WoutT   = WdtT + (size_t)DINNER * DTRANK; // [DMODEL][DINNER]
    f16*   big     = WoutT + (size_t)DMODEL * DINNER;// 16.78M f16 alias region
    f16*   WinT    = big;                            // [NXZ][DMODEL] (phase 1)
    float* part3   = (float*)(big + (size_t)NXZ * DMODEL);  // [8][MTOK][96] (phase 2)
    f16*   ygh     = big;                            // [MTOK][DINNER] (phase 3)
    f16*   xh      = uh;                             // [MTOK][DMODEL] (pre-conv alias)
    f16*   uph     = (f16*)updelta;                  // [MTOK][DINNER] f16 (dead before delta)
    f16*   deltah  = (f16*)updelta;                  // [MTOK][DINNER] f16 (over uph)

    // 1) convert x, transpose-convert W_in
    cvt_f2h<<<(MTOK * DMODEL / 4 + 255) / 256, 256, 0, stream>>>(x, xh, MTOK * DMODEL / 4);
    tcvt<<<dim3(NXZ / 32, DMODEL / 32), 256, 0, stream>>>(W_in, WinT, DMODEL, NXZ);

    // 2) GEMM1: [u_pre | z] = x @ W_in, single dispatch, split outputs
    hgemm128<0, f16><<<dim3(64, 32), 256, 0, stream>>>(
        xh, DMODEL, WinT, DMODEL, uph, DINNER, DMODEL, nullptr, zh, DINNER);

    // 3) conv + silu -> uh f16   (clobbers xh)
    conv_silu_kernel<<<MTOK / 8, 256, 0, stream>>>(uph, cw, cb, uh);

    // 4) proj = u @ W_xproj  (split-K=8, N=96) + reduce
    tcvt<<<dim3(96 / 32, DINNER / 32), 256, 0, stream>>>(W_xp, WxpT, DINNER, 96);
    hgemm_n96<<<dim3(64, SPLITK), 256, 0, stream>>>(uh, WxpT, part3);
    reduce3<<<NPROJ / 256, 256, 0, stream>>>(part3, proj, projh);

    // 5) deltah = softplus(proj[:, :64] @ W_dt + b_dt) f16 (uph dead)
    tcvt<<<dim3(DINNER / 32, DTRANK / 32), 256, 0, stream>>>(W_dt, WdtT, DTRANK, DINNER);
    hgemm128<1, f16><<<dim3(64, 16), 256, 0, stream>>>(
        projh, 96, WdtT, DTRANK, deltah, DINNER, DTRANK, b_dt, nullptr, 0);

    // 6) chunked scan + skip + gate -> ygh f16 (clobbers WinT/part3)
    scan_pass1<<<dim3(DINNER / 256, NCH, NBATCH), 256, 0, stream>>>(
        uh, deltah, proj, A_log, Sbuf, sumdt);
    scan_pass2<<<dim3(DINNER / 256, NBATCH), 256, 0, stream>>>(A_log, sumdt, Sbuf);
    scan_pass3<<<dim3(DINNER / 256, NCH, NBATCH), 256, 0, stream>>>(
        uh, deltah, zh, proj, A_log, Dp, Sbuf, ygh);

    // 7) out = yg @ W_out
    tcvt<<<dim3(DMODEL / 32, DINNER / 32), 256, 0, stream>>>(W_out, WoutT, DINNER, DMODEL);
    hgemm128<0, float><<<dim3(64, 8), 256, 0, stream>>>(
        ygh, DINNER, WoutT, DINNER, out, DMODEL, DINNER, nullptr, nullptr, 0);
}